// Round 11
// baseline (340.203 us; speedup 1.0000x reference)
//
#include <hip/hip_runtime.h>

typedef __attribute__((ext_vector_type(8))) short short8;
typedef __attribute__((ext_vector_type(4))) short short4v;
typedef __attribute__((ext_vector_type(4))) float f32x4;

__device__ __forceinline__ short f2bf(float x) {
    union { float f; unsigned u; } c; c.f = x;
    unsigned u = c.u;
    u += 0x7fffu + ((u >> 16) & 1u);
    return (short)(u >> 16);
}

// ---------------------------------------------------------------------------
// fp32 -> bf16 bulk convert for vis_tokens
__global__ __launch_bounds__(256) void cvt_bf16(const float* __restrict__ s, short* __restrict__ d, int n4) {
    int i = blockIdx.x * 256 + threadIdx.x;
    if (i < n4) {
        float4 v = ((const float4*)s)[i];
        short4 o;
        o.x = f2bf(v.x); o.y = f2bf(v.y); o.z = f2bf(v.z); o.w = f2bf(v.w);
        ((short4*)d)[i] = o;
    }
}

// combined small converts (float4 counts): emb_w 32768, k_w 16384, v_w 16384
__global__ __launch_bounds__(256) void cvt3(const float* __restrict__ emb, const float* __restrict__ kw,
                                            const float* __restrict__ vw,
                                            short* __restrict__ de, short* __restrict__ dk, short* __restrict__ dv) {
    int i = blockIdx.x * 256 + threadIdx.x;   // 0..65535
    const float* s; short* d; int off;
    if (i < 32768) { s = emb; d = de; off = i; }
    else if (i < 49152) { s = kw; d = dk; off = i - 32768; }
    else { s = vw; d = dv; off = i - 49152; }
    float4 v = ((const float4*)s)[off];
    short4 o;
    o.x = f2bf(v.x); o.y = f2bf(v.y); o.z = f2bf(v.z); o.w = f2bf(v.w);
    ((short4*)d)[off] = o;
}

// ---------------------------------------------------------------------------
// Fold conv into W_fold^T; blockIdx.y selects side. (coalesced: ci=block, j=thread)
__global__ void build_wfold(const float* __restrict__ cl, const float* __restrict__ cr,
                            float* __restrict__ wfT) {
    const float* conv_w = blockIdx.y ? cr : cl;
    float* o = wfT + (long)blockIdx.y * 327680;
    const int ci = blockIdx.x;
    const int j = threadIdx.x;
    float acc[5] = {0.f, 0.f, 0.f, 0.f, 0.f};
#pragma unroll
    for (int i = 0; i < 5; ++i) {
        int flat = i * 256 + j;
        int c = flat / 5;
        int s = flat % 5;
#pragma unroll
        for (int k = 0; k < 3; ++k) {
            int si = s + k - 1;
            if (si >= 0 && si < 5) acc[si] += conv_w[(c * 256 + ci) * 3 + k];
        }
    }
#pragma unroll
    for (int si = 0; si < 5; ++si)
        o[(si * 256 + ci) * 256 + j] = acc[si] * 0.2f;
}

// ---------------------------------------------------------------------------
// fp32 tiled GEMM (small P-build path): C[row,col]=sum A[row,k]W[col,k]
template <bool BIAS>
__global__ __launch_bounds__(256) void gemm64(const float* __restrict__ A,
                                              const float* __restrict__ W,
                                              const float* __restrict__ bias,
                                              float* __restrict__ C,
                                              int K, int ldC,
                                              long sliceA, long sliceW, long sliceC) {
    A += (long)blockIdx.z * sliceA;
    W += (long)blockIdx.z * sliceW;
    C += (long)blockIdx.z * sliceC;
    const int row0 = blockIdx.x * 64;
    const int col0 = blockIdx.y * 64;
    __shared__ float As[32][68];
    __shared__ float Ws[32][68];
    const int t = threadIdx.x;
    const int tx = t & 15;
    const int ty = t >> 4;
    float acc[4][4] = {};
    for (int kk = 0; kk < K; kk += 32) {
#pragma unroll
        for (int e = 0; e < 8; ++e) {
            int f = t + 256 * e;
            int r = f >> 5, kc = f & 31;
            As[kc][r] = A[(long)(row0 + r) * K + kk + kc];
            Ws[kc][r] = W[(long)(col0 + r) * K + kk + kc];
        }
        __syncthreads();
#pragma unroll
        for (int kc = 0; kc < 32; ++kc) {
            float4 a4 = *(const float4*)&As[kc][ty * 4];
            float4 w4 = *(const float4*)&Ws[kc][tx * 4];
            float av[4] = {a4.x, a4.y, a4.z, a4.w};
            float wv[4] = {w4.x, w4.y, w4.z, w4.w};
#pragma unroll
            for (int i = 0; i < 4; ++i)
#pragma unroll
                for (int jj = 0; jj < 4; ++jj)
                    acc[i][jj] += av[i] * wv[jj];
        }
        __syncthreads();
    }
#pragma unroll
    for (int r = 0; r < 4; ++r) {
        int row = row0 + ty * 4 + r;
#pragma unroll
        for (int c = 0; c < 4; ++c) {
            int col = col0 + tx * 4 + c;
            float v = acc[r][c];
            if (BIAS) v += bias[col];
            C[(long)row * ldC + col] = v;
        }
    }
}

// ---------------------------------------------------------------------------
// bf16 MFMA GEMM (classifier): C = A.W^T + bias, fp32 out.
// Round-11: restructured onto the proven gemm_ln skeleton — block = 64 rows
// x 256 cols, 4 waves each owning a 64x64 sub-tile via acc[4][4] (16 MFMA
// per wave per K-step vs 4 in the old 64x64-block version). A amplification
// drops 8x -> 2x; W (embbf, 262KB) is L2-resident. Grid (128, 2, 2) = 512
// blocks = 2/CU. Fragment/epilogue mapping copied verbatim from gemm_ln's
// verified C-write (row = mi*16+quad*4+r, col = wid*64+ni*16+sub).
__global__ __launch_bounds__(256) void gemm_bf(const short* __restrict__ A,
                                               const short* __restrict__ W,
                                               const float* __restrict__ bias,
                                               float* __restrict__ Cf,
                                               int K, int ldC,
                                               long sliceA, long sliceC) {
    A += (long)blockIdx.z * sliceA;
    const int row0 = blockIdx.x * 64;
    const int colh = blockIdx.y * 256;          // 256-col half owned by block
    __shared__ short As[64 * 40];
    __shared__ short Ws[256 * 40];
    const int t = threadIdx.x;
    const int wid = t >> 6, lane = t & 63, sub = lane & 15, quad = lane >> 4;
    f32x4 acc[4][4];
#pragma unroll
    for (int mi = 0; mi < 4; ++mi)
#pragma unroll
        for (int ni = 0; ni < 4; ++ni) acc[mi][ni] = (f32x4){0.f, 0.f, 0.f, 0.f};

    const int sr = t >> 2, sseg = t & 3;
    for (int kk = 0; kk < 256; kk += 32) {
        *(short8*)&As[sr * 40 + sseg * 8] = *(const short8*)&A[(long)(row0 + sr) * K + kk + sseg * 8];
#pragma unroll
        for (int i = 0; i < 4; ++i) {
            int r = i * 64 + sr;
            *(short8*)&Ws[r * 40 + sseg * 8] = *(const short8*)&W[(long)(colh + r) * K + kk + sseg * 8];
        }
        __syncthreads();
        short8 a[4], b[4];
#pragma unroll
        for (int mi = 0; mi < 4; ++mi) a[mi] = *(const short8*)&As[(mi * 16 + sub) * 40 + quad * 8];
#pragma unroll
        for (int ni = 0; ni < 4; ++ni) b[ni] = *(const short8*)&Ws[(wid * 64 + ni * 16 + sub) * 40 + quad * 8];
#pragma unroll
        for (int mi = 0; mi < 4; ++mi)
#pragma unroll
            for (int ni = 0; ni < 4; ++ni)
                acc[mi][ni] = __builtin_amdgcn_mfma_f32_16x16x32_bf16(a[mi], b[ni], acc[mi][ni], 0, 0, 0);
        __syncthreads();
    }
    Cf += (long)blockIdx.z * sliceC;
#pragma unroll
    for (int ni = 0; ni < 4; ++ni) {
        const int col = colh + wid * 64 + ni * 16 + sub;
        const float bv = bias[col];
#pragma unroll
        for (int mi = 0; mi < 4; ++mi)
#pragma unroll
            for (int r = 0; r < 4; ++r) {
                const int row = row0 + mi * 16 + quad * 4 + r;
                Cf[(long)row * ldC + col] = acc[mi][ni][r] + bv;
            }
    }
}

// ---------------------------------------------------------------------------
// K/V projection + bias + row LayerNorm fused; V written transposed into Vt.
__global__ __launch_bounds__(256) void gemm_ln(const short* __restrict__ A,
                                               const short* __restrict__ kwbf, const short* __restrict__ vwbf,
                                               const float* __restrict__ k_b, const float* __restrict__ v_b,
                                               const float* __restrict__ gamma, const float* __restrict__ beta,
                                               short* __restrict__ Kout, short* __restrict__ Vt) {
    const bool isV = blockIdx.y != 0;
    const short* W = isV ? vwbf : kwbf;
    const float* bias = isV ? v_b : k_b;
    const int row0 = blockIdx.x * 64;
    __shared__ short As[64 * 40];
    __shared__ short Ws[256 * 40];
    __shared__ float s_mu[64 * 4];
    __shared__ float s_sq[64 * 4];
    __shared__ float s_mv[64 * 2];
    const int t = threadIdx.x;
    const int wid = t >> 6, lane = t & 63, sub = lane & 15, quad = lane >> 4;
    f32x4 acc[4][4];
#pragma unroll
    for (int mi = 0; mi < 4; ++mi)
#pragma unroll
        for (int ni = 0; ni < 4; ++ni) acc[mi][ni] = (f32x4){0.f, 0.f, 0.f, 0.f};

    const int sr = t >> 2, sseg = t & 3;
    for (int kk = 0; kk < 256; kk += 32) {
        *(short8*)&As[sr * 40 + sseg * 8] = *(const short8*)&A[(long)(row0 + sr) * 256 + kk + sseg * 8];
#pragma unroll
        for (int i = 0; i < 4; ++i) {
            int r = i * 64 + sr;
            *(short8*)&Ws[r * 40 + sseg * 8] = *(const short8*)&W[(long)r * 256 + kk + sseg * 8];
        }
        __syncthreads();
        short8 a[4], b[4];
#pragma unroll
        for (int mi = 0; mi < 4; ++mi) a[mi] = *(const short8*)&As[(mi * 16 + sub) * 40 + quad * 8];
#pragma unroll
        for (int ni = 0; ni < 4; ++ni) b[ni] = *(const short8*)&Ws[(wid * 64 + ni * 16 + sub) * 40 + quad * 8];
#pragma unroll
        for (int mi = 0; mi < 4; ++mi)
#pragma unroll
            for (int ni = 0; ni < 4; ++ni)
                acc[mi][ni] = __builtin_amdgcn_mfma_f32_16x16x32_bf16(a[mi], b[ni], acc[mi][ni], 0, 0, 0);
        __syncthreads();
    }
#pragma unroll
    for (int ni = 0; ni < 4; ++ni) {
        float bv = bias[wid * 64 + ni * 16 + sub];
#pragma unroll
        for (int mi = 0; mi < 4; ++mi)
#pragma unroll
            for (int r = 0; r < 4; ++r) acc[mi][ni][r] += bv;
    }
#pragma unroll
    for (int mi = 0; mi < 4; ++mi) {
#pragma unroll
        for (int r = 0; r < 4; ++r) {
            float s = 0.f, q2 = 0.f;
#pragma unroll
            for (int ni = 0; ni < 4; ++ni) {
                float v = acc[mi][ni][r];
                s += v; q2 += v * v;
            }
#pragma unroll
            for (int off = 8; off; off >>= 1) {
                s += __shfl_xor(s, off, 16);
                q2 += __shfl_xor(q2, off, 16);
            }
            if (sub == 0) {
                int row = mi * 16 + quad * 4 + r;
                s_mu[row * 4 + wid] = s;
                s_sq[row * 4 + wid] = q2;
            }
        }
    }
    __syncthreads();
    if (t < 64) {
        float s = s_mu[t * 4] + s_mu[t * 4 + 1] + s_mu[t * 4 + 2] + s_mu[t * 4 + 3];
        float q2 = s_sq[t * 4] + s_sq[t * 4 + 1] + s_sq[t * 4 + 2] + s_sq[t * 4 + 3];
        float mean = s * (1.0f / 256.0f);
        float var = q2 * (1.0f / 256.0f) - mean * mean;
        s_mv[t * 2] = mean;
        s_mv[t * 2 + 1] = rsqrtf(var + 1e-5f);
    }
    __syncthreads();
#pragma unroll
    for (int ni = 0; ni < 4; ++ni) {
        int col = wid * 64 + ni * 16 + sub;
        float g = gamma[col], bb = beta[col];
        if (!isV) {
#pragma unroll
            for (int mi = 0; mi < 4; ++mi)
#pragma unroll
                for (int r = 0; r < 4; ++r) {
                    int row = mi * 16 + quad * 4 + r;
                    float v = (acc[mi][ni][r] - s_mv[row * 2]) * s_mv[row * 2 + 1] * g + bb;
                    Kout[(long)(row0 + row) * 256 + col] = f2bf(v);
                }
        } else {
            int h = col >> 5, dh = col & 31;
#pragma unroll
            for (int mi = 0; mi < 4; ++mi) {
                int rowb = row0 + mi * 16 + quad * 4;
                short4 o;
#pragma unroll
                for (int r = 0; r < 4; ++r) {
                    int row = mi * 16 + quad * 4 + r;
                    float v = (acc[mi][ni][r] - s_mv[row * 2]) * s_mv[row * 2 + 1] * g + bb;
                    ((short*)&o)[r] = f2bf(v);
                }
                int gb = rowb >> 10, n = rowb & 1023;
                *(short4*)&Vt[((long)(gb * 8 + h) * 32 + dh) * 1024 + n] = o;
            }
        }
    }
}

// ---------------------------------------------------------------------------
// bias_dir: wave-per-8-outputs, coalesced j sweep + shuffle reduce.
__global__ __launch_bounds__(256) void bias_dir_kernel(const float* __restrict__ tp, const float* __restrict__ tpb,
                                                       const float* __restrict__ dirL, const float* __restrict__ dirR,
                                                       float* __restrict__ biasL, float* __restrict__ biasR) {
    const float* dir = blockIdx.y ? dirR : dirL;
    float* outp = blockIdx.y ? biasR : biasL;
    __shared__ float sdir[256];
    sdir[threadIdx.x] = dir[threadIdx.x];
    __syncthreads();
    const int wid = threadIdx.x >> 6, lane = threadIdx.x & 63;
#pragma unroll
    for (int i = 0; i < 8; ++i) {
        const int d = blockIdx.x * 32 + wid * 8 + i;
        float p = 0.f;
#pragma unroll
        for (int jj = 0; jj < 4; ++jj)
            p += tp[d * 256 + jj * 64 + lane] * sdir[jj * 64 + lane];
#pragma unroll
        for (int off = 32; off; off >>= 1) p += __shfl_xor(p, off, 64);
        if (lane == 0) outp[d] = p + tpb[d];
    }
}

// ---------------------------------------------------------------------------
// Q build, wave-per-row: gather 5 P rows, + dir bias, LN, bf16 out.
__global__ __launch_bounds__(256) void q_build(const int* __restrict__ idsL, const int* __restrict__ idsR,
                                               const float* __restrict__ Pp,
                                               const float* __restrict__ biasL, const float* __restrict__ biasR,
                                               const float* __restrict__ qg, const float* __restrict__ qb,
                                               short* __restrict__ Qbf) {
    const int wid = threadIdx.x >> 6, lane = threadIdx.x & 63;
    const int bl = blockIdx.x * 4 + wid;
    const bool right = blockIdx.y != 0;
    const int* ids = right ? idsR : idsL;
    const float* P = right ? Pp + 655360 : Pp;
    const float* bias = right ? biasR : biasL;
    const int d0 = lane * 4;
    float4 acc = *(const float4*)&bias[d0];
#pragma unroll
    for (int s = 0; s < 5; ++s) {
        int tok = ids[bl * 5 + s];
        float4 p = *(const float4*)&P[(long)(s * 512 + tok) * 256 + d0];
        acc.x += p.x; acc.y += p.y; acc.z += p.z; acc.w += p.w;
    }
    float sum = acc.x + acc.y + acc.z + acc.w;
    float sq = acc.x * acc.x + acc.y * acc.y + acc.z * acc.z + acc.w * acc.w;
#pragma unroll
    for (int off = 32; off; off >>= 1) {
        sum += __shfl_xor(sum, off, 64);
        sq += __shfl_xor(sq, off, 64);
    }
    float mean = sum * (1.0f / 256.0f);
    float var = sq * (1.0f / 256.0f) - mean * mean;
    float rstd = rsqrtf(var + 1e-5f);
    float4 g = *(const float4*)&qg[d0];
    float4 bb = *(const float4*)&qb[d0];
    short4 o;
    o.x = f2bf((acc.x - mean) * rstd * g.x + bb.x);
    o.y = f2bf((acc.y - mean) * rstd * g.y + bb.y);
    o.z = f2bf((acc.z - mean) * rstd * g.z + bb.z);
    o.w = f2bf((acc.w - mean) * rstd * g.w + bb.w);
    *(short4*)&Qbf[(right ? 2097152L : 0L) + (long)bl * 256 + d0] = o;
}

// ---------------------------------------------------------------------------
// One 32-n chunk for 64 l rows (4 Q-frags), ONE side (L/R split across
// waves). Mask from LDS (fp32, bit-exact), XOR-swizzled n4^(l&7). Math
// identical to the round-5-proven kernel, minus the R half.
__device__ __forceinline__ void proc_chunk(
    short8 ak0, short8 ak1, short4v v00, short4v v01, short4v v10, short4v v11,
    const float* mlds, int sub, int quad, float inv2,
    const short8 (&bq)[4],
    f32x4 (&o)[4][2], float (&ps)[4]) {
    short8 av0, av1;
#pragma unroll
    for (int j = 0; j < 4; ++j) {
        av0[j] = v00[j]; av0[4 + j] = v01[j];
        av1[j] = v10[j]; av1[4 + j] = v11[j];
    }
    const int sw = (quad ^ (sub & 7)) << 2;
#pragma unroll
    for (int lt = 0; lt < 4; ++lt) {
        const int mi = ((lt * 16 + sub) << 5) + sw;
        float4 mk0 = *(const float4*)&mlds[mi];
        float4 mk1 = *(const float4*)&mlds[mi ^ 16];
        float m0x = mk0.x * inv2, m0y = mk0.y * inv2, m0z = mk0.z * inv2, m0w = mk0.w * inv2;
        float m1x = mk1.x * inv2, m1y = mk1.y * inv2, m1z = mk1.z * inv2, m1w = mk1.w * inv2;
        f32x4 c0 = {0.f, 0.f, 0.f, 0.f}, c1 = c0;
        c0 = __builtin_amdgcn_mfma_f32_16x16x32_bf16(ak0, bq[lt], c0, 0, 0, 0);
        c1 = __builtin_amdgcn_mfma_f32_16x16x32_bf16(ak1, bq[lt], c1, 0, 0, 0);
        float p0 = __builtin_amdgcn_exp2f(c0[0] * m0x);
        float p1 = __builtin_amdgcn_exp2f(c0[1] * m0y);
        float p2 = __builtin_amdgcn_exp2f(c0[2] * m0z);
        float p3 = __builtin_amdgcn_exp2f(c0[3] * m0w);
        float p4 = __builtin_amdgcn_exp2f(c1[0] * m1x);
        float p5 = __builtin_amdgcn_exp2f(c1[1] * m1y);
        float p6 = __builtin_amdgcn_exp2f(c1[2] * m1z);
        float p7 = __builtin_amdgcn_exp2f(c1[3] * m1w);
        ps[lt] += ((p0 + p1) + (p2 + p3)) + ((p4 + p5) + (p6 + p7));
        short8 p8;
        p8[0] = f2bf(p0); p8[1] = f2bf(p1); p8[2] = f2bf(p2); p8[3] = f2bf(p3);
        p8[4] = f2bf(p4); p8[5] = f2bf(p5); p8[6] = f2bf(p6); p8[7] = f2bf(p7);
        o[lt][0] = __builtin_amdgcn_mfma_f32_16x16x32_bf16(av0, p8, o[lt][0], 0, 0, 0);
        o[lt][1] = __builtin_amdgcn_mfma_f32_16x16x32_bf16(av1, p8, o[lt][1], 0, 0, 0);
    }
}

// ---------------------------------------------------------------------------
// MFMA cross-attention v4b: side-split, launch_bounds(512,1).
// Measured round-10: VGPR 112, no spill, FETCH 37.8MB, dur ~72us (= round-8's
// two-sided 70.9 within noise) at ~20% occupancy — the 2nd block/CU did not
// co-reside and wave-latency is NOT the binding constraint; the 16-barrier
// lockstep pipeline is (~13% utilization). Kept as-is; pivot to non-attn.
__global__ __launch_bounds__(512, 1) void attn_wave(const short* __restrict__ Qbf,
                                                    const short* __restrict__ Kbf,
                                                    const short* __restrict__ Vt,
                                                    const float* __restrict__ vis_mask,
                                                    const float* __restrict__ tau_p,
                                                    short* __restrict__ Fbf) {
    const int t = threadIdx.x;
    const int wid = t >> 6, lane = t & 63, sub = lane & 15, quad = lane >> 4;
    // bijective XCD swizzle over 512 blocks (64 per XCD)
    const int gb = ((blockIdx.x & 7) << 6) | (blockIdx.x >> 3);
    const int b = gb >> 4;            // 0..31
    const int lb = (gb >> 2) & 3;     // 0..3  (64-l block)
    const int hp = gb & 3;            // 0..3  (h pair)
    const int wh = wid >> 2;          // h in pair
    const int side = (wid >> 1) & 1;  // 0 = L, 1 = R
    const int nh = wid & 1;           // n-half
    const int h = hp * 2 + wh;        // 0..7
    const int l0 = lb * 64;
    float tau = fminf(fmaxf(tau_p[0], 0.25f), 4.0f);
    const float inv2 = 1.4426950408889634f / (5.656854249492381f * tau);

    // mask LDS: [2 buf][2 nh][64 l][8 n4'][4] floats = 32 KB, n4' = n4^(l&7)
    __shared__ float mbuf[2 * 4096];
    // combine buffer: pair p = (wh,side), payload o(32)+ps(4) @ stride 40
    __shared__ float red[4][64][40];

    // staging precompute: thread t owns 16B slots s0=2t, s1=2t+1
    const int s0 = t * 2;
    const int l_s = (s0 >> 3) & 63, nh_s = s0 >> 9;
    const int n4a = s0 & 7, n4b = n4a + 1;
    const float* mrow0 = vis_mask + (long)(b * 256 + l0 + l_s) * 1024 + nh_s * 512 + 4 * (n4a ^ (l_s & 7));
    const float* mrow1 = vis_mask + (long)(b * 256 + l0 + l_s) * 1024 + nh_s * 512 + 4 * (n4b ^ (l_s & 7));
    float* mdst0 = mbuf + nh_s * 2048 + l_s * 32 + n4a * 4;
    float* mdst1 = mbuf + nh_s * 2048 + l_s * 32 + n4b * 4;

    // Q B-frags for 4 l-tiles, this wave's side only
    const short* Qside = Qbf + (side ? 2097152L : 0L);
    short8 bq[4];
#pragma unroll
    for (int lt = 0; lt < 4; ++lt) {
        const long qoff = (long)(b * 256 + l0 + lt * 16 + sub) * 256 + h * 32 + quad * 8;
        bq[lt] = *(const short8*)&Qside[qoff];
    }

    const short* Kb = Kbf + (long)b * 262144 + h * 32;            // + n*256 + quad*8
    const short* Vb = Vt + (long)(b * 8 + h) * 32768;             // Vt[dh][n]
    const float* mld = mbuf + nh * 2048;                          // this wave's nh half

    f32x4 o[4][2];
    float ps[4];
#pragma unroll
    for (int lt = 0; lt < 4; ++lt) {
        o[lt][0] = (f32x4){0.f, 0.f, 0.f, 0.f}; o[lt][1] = o[lt][0];
        ps[lt] = 0.f;
    }

    const int nbeg = nh << 9;   // n-half [nbeg, nbeg+512)

#define LOADK(A0, A1, N)                                                      \
    A0 = *(const short8*)&Kb[(long)((N) + sub) * 256 + quad * 8];             \
    A1 = *(const short8*)&Kb[(long)((N) + 16 + sub) * 256 + quad * 8];
#define LOADV(W00, W01, W10, W11, N)                                          \
    W00 = *(const short4v*)&Vb[(long)sub * 1024 + (N) + quad * 4];            \
    W01 = *(const short4v*)&Vb[(long)sub * 1024 + (N) + 16 + quad * 4];       \
    W10 = *(const short4v*)&Vb[(long)(16 + sub) * 1024 + (N) + quad * 4];     \
    W11 = *(const short4v*)&Vb[(long)(16 + sub) * 1024 + (N) + 16 + quad * 4];

    short8 ak0A, ak1A, ak0B, ak1B;
    short4v v00A, v01A, v10A, v11A, v00B, v01B, v10B, v11B;
    float4 mr0, mr1;

    // prologue: stage mask chunk 0 into buf0, prefetch K/V chunk 0
    mr0 = *(const float4*)&mrow0[0];
    mr1 = *(const float4*)&mrow1[0];
    *(float4*)&mdst0[0] = mr0;
    *(float4*)&mdst1[0] = mr1;
    LOADK(ak0A, ak1A, nbeg)
    LOADV(v00A, v01A, v10A, v11A, nbeg)
    __syncthreads();

#pragma unroll 1
    for (int j = 0; j < 8; ++j) {
        const int n0 = nbeg + j * 64;
        // ---- chunk 2j (mask buf0) ----
        LOADK(ak0B, ak1B, n0 + 32)
        LOADV(v00B, v01B, v10B, v11B, n0 + 32)
        {   // load mask chunk 2j+1 (always valid) into regs
            const int nrel = j * 64 + 32;
            mr0 = *(const float4*)&mrow0[nrel];
            mr1 = *(const float4*)&mrow1[nrel];
        }
        proc_chunk(ak0A, ak1A, v00A, v01A, v10A, v11A, mld, sub, quad, inv2,
                   bq, o, ps);
        *(float4*)&mdst0[4096] = mr0;       // write chunk 2j+1 -> buf1
        *(float4*)&mdst1[4096] = mr1;
        __syncthreads();
        // ---- chunk 2j+1 (mask buf1) ----
        const int nx = (j < 7) ? n0 + 64 : nbeg;     // last prefetch = dummy (hot)
        LOADK(ak0A, ak1A, nx)
        LOADV(v00A, v01A, v10A, v11A, nx)
        {   // load mask chunk 2j+2 (dummy reload of chunk0 at j=7)
            const int nrel = (j < 7) ? j * 64 + 64 : 0;
            mr0 = *(const float4*)&mrow0[nrel];
            mr1 = *(const float4*)&mrow1[nrel];
        }
        proc_chunk(ak0B, ak1B, v00B, v01B, v10B, v11B, mld + 4096, sub, quad, inv2,
                   bq, o, ps);
        *(float4*)&mdst0[0] = mr0;          // write chunk 2j+2 -> buf0 (dummy at j=7)
        *(float4*)&mdst1[0] = mr1;
        __syncthreads();
    }
#undef LOADK
#undef LOADV

    // full row-sums per l-tile for l = sub (combine the 4 quads)
#pragma unroll
    for (int lt = 0; lt < 4; ++lt) {
        ps[lt] += __shfl_xor(ps[lt], 16, 64);
        ps[lt] += __shfl_xor(ps[lt], 32, 64);
    }

    // cross n-half combine within (wh, side) pair: nh==1 publishes,
    // one barrier, nh==0 adds. layout per lane: [0..31]=o, [32..35]=ps.
    const int pr = wid >> 1;   // pair index = wh*2+side
    if (nh == 1) {
        float* p = &red[pr][lane][0];
#pragma unroll
        for (int lt = 0; lt < 4; ++lt) {
            *(f32x4*)(p + lt * 8) = o[lt][0];
            *(f32x4*)(p + lt * 8 + 4) = o[lt][1];
            p[32 + lt] = ps[lt];
        }
    }
    __syncthreads();
    if (nh == 1) return;
    {
        const float* p = &red[pr][lane][0];
#pragma unroll
        for (int lt = 0; lt < 4; ++lt) {
            f32x4 e0 = *(const f32x4*)(p + lt * 8);
            f32x4 e1 = *(const f32x4*)(p + lt * 8 + 4);
#pragma unroll
            for (int q = 0; q < 4; ++q) {
                o[lt][0][q] += e0[q];
                o[lt][1][q] += e1[q];
            }
            ps[lt] += p[32 + lt];
        }
    }

    // O^T[4*quad+r (+16)][l] -> F[b,l][h*32 + 4*quad + r (+16)]
    short* Fside = Fbf + (side ? 2097152L : 0L);
#pragma unroll
    for (int lt = 0; lt < 4; ++lt) {
        const long fo = (long)(b * 256 + l0 + lt * 16 + sub) * 256 + h * 32 + quad * 4;
        const float rS = 1.0f / ps[lt];
        short4v s0v, s1v;
#pragma unroll
        for (int r = 0; r < 4; ++r) { s0v[r] = f2bf(o[lt][0][r] * rS); s1v[r] = f2bf(o[lt][1][r] * rS); }
        *(short4v*)&Fside[fo] = s0v;
        *(short4v*)&Fside[fo + 16] = s1v;
    }
}

// ---------------------------------------------------------------------------
// Loss: wave per (b,l) pair; block-level reduce, one plain store per block.
__global__ __launch_bounds__(256) void loss_pair(const float* __restrict__ logits,
                                                 const float* __restrict__ tgt_mask,
                                                 float* __restrict__ partials) {
    const int wid = threadIdx.x >> 6, lane = threadIdx.x & 63;
    const int pid = blockIdx.x * 4 + wid;   // 0..8159
    const int b = pid / 255, l = pid - b * 255;
    const float* ll = logits + (long)(b * 256 + l) * 512;
    const float* lr = logits + 4194304 + (long)(b * 256 + l + 1) * 512;
    float a[8], c[8];
#pragma unroll
    for (int j = 0; j < 8; ++j) {
        a[j] = ll[lane + 64 * j] * 0.5f;
        c[j] = lr[lane + 64 * j] * 0.5f;
    }
    float ml = -1e30f, mr = -1e30f;
#pragma unroll
    for (int j = 0; j < 8; ++j) { ml = fmaxf(ml, a[j]); mr = fmaxf(mr, c[j]); }
#pragma unroll
    for (int off = 32; off; off >>= 1) {
        ml = fmaxf(ml, __shfl_xor(ml, off, 64));
        mr = fmaxf(mr, __shfl_xor(mr, off, 64));
    }
    float sl = 0.f, sr = 0.f;
#pragma unroll
    for (int j = 0; j < 8; ++j) {
        a[j] = __expf(a[j] - ml); sl += a[j];
        c[j] = __expf(c[j] - mr); sr += c[j];
    }
#pragma unroll
    for (int off = 32; off; off >>= 1) {
        sl += __shfl_xor(sl, off, 64);
        sr += __shfl_xor(sr, off, 64);
    }
    float rl = 1.0f / sl, rr = 1.0f / sr;
    float sq = 0.f;
#pragma unroll
    for (int j = 0; j < 8; ++j) {
        float d = a[j] * rl - c[j] * rr;
        sq += d * d;
    }
#pragma unroll
    for (int off = 32; off; off >>= 1) sq += __shfl_xor(sq, off, 64);

    __shared__ float sred[4];
    if (lane == 0) sred[wid] = sq * tgt_mask[b * 256 + l];
    __syncthreads();
    if (threadIdx.x == 0)
        partials[blockIdx.x] = (sred[0] + sred[1]) + (sred[2] + sred[3]);
}

__global__ __launch_bounds__(256) void loss_final(const float* __restrict__ tgt_mask,
                                                  const float* __restrict__ partials,
                                                  float* __restrict__ outp) {
    const int t = threadIdx.x;
    float s = 0.f, acc = 0.f;
    for (int i = t; i < 32 * 255; i += 256) {
        int b = i / 255, l = i % 255;
        s += tgt_mask[b * 256 + l];
    }
    for (int i = t; i < 2040; i += 256) acc += partials[i];
    __shared__ float red[256];
    __shared__ float reda[256];
    red[t] = s;
    reda[t] = acc;
    __syncthreads();
    for (int st = 128; st; st >>= 1) {
        if (t < st) { red[t] += red[t + st]; reda[t] += reda[t + st]; }
        __syncthreads();
    }
    if (t == 0) outp[0] = 0.1f * reda[0] / fmaxf(red[0], 1.0f);
}

// ---------------------------------------------------------------------------
extern "C" void kernel_launch(void* const* d_in, const int* in_sizes, int n_in,
                              void* d_out, int out_size, void* d_ws, size_t ws_size,
                              hipStream_t stream) {
    const float* vis_tokens = (const float*)d_in[0];
    const int* idsL = (const int*)d_in[1];
    const int* idsR = (const int*)d_in[2];
    const float* tgt_mask = (const float*)d_in[4];
    const float* vis_mask = (const float*)d_in[5];
    const float* emb_w = (const float*)d_in[6];
    const float* dirL = (const float*)d_in[7];
    const float* dirR = (const float*)d_in[8];
    const float* tp_w = (const float*)d_in[9];
    const float* tp_b = (const float*)d_in[10];
    const float* q_g = (const float*)d_in[11];
    const float* q_b = (const float*)d_in[12];
    const float* k_w = (const float*)d_in[13];
    const float* k_b = (const float*)d_in[14];
    const float* v_w = (const float*)d_in[15];
    const float* v_b = (const float*)d_in[16];
    const float* kv_g = (const float*)d_in[17];
    const float* kv_b = (const float*)d_in[18];
    const float* tau = (const float*)d_in[19];
    const float* cls_b = (const float*)d_in[20];
    const float* conv_l = (const float*)d_in[21];
    const float* conv_r = (const float*)d_in[22];
    float* out = (float*)d_out;

    // ---- workspace layout ----
    short* sws = (short*)d_ws;
    short* visbf = sws;                         // 8,388,608
    short* embbf = visbf + 8388608;             // 131,072
    short* kwbf  = embbf + 131072;              // 65,536
    short* vwbf  = kwbf + 65536;                // 65,536
    short* Kbf   = vwbf + 65536;                // 8,388,608
    short* Vt    = Kbf + 8388608;               // 8,388,608
    short* Qbf   = Vt + 8388608;                // 4,194,304 (L|R)
    short* Fbf   = Qbf + 4194304;               // 4,194,304 (L|R)
    float* wfT   = (float*)(Fbf + 4194304);     // 10 slices x 65536
    float* Ms    = wfT + 655360;                // 10 x 65536
    float* Pp    = Ms + 655360;                 // 10 x 131072
    float* bias_l = Pp + 1310720;
    float* bias_r = bias_l + 256;
    float* partials = bias_r + 256;             // 2040 floats

    // ---- converts ----
    cvt_bf16<<<8192, 256, 0, stream>>>(vis_tokens, visbf, 2097152);
    cvt3<<<256, 256, 0, stream>>>(emb_w, k_w, v_w, embbf, kwbf, vwbf);

    // ---- ctx path: wfold -> Ms -> P (fp32, small) ----
    build_wfold<<<dim3(256, 2), 256, 0, stream>>>(conv_l, conv_r, wfT);
    gemm64<false><<<dim3(4, 4, 10), 256, 0, stream>>>(tp_w, wfT, nullptr, Ms, 256, 256, 0, 65536, 65536);
    gemm64<false><<<dim3(8, 4, 10), 256, 0, stream>>>(emb_w, Ms, nullptr, Pp, 256, 256, 0, 65536, 131072);
    bias_dir_kernel<<<dim3(8, 2), 256, 0, stream>>>(tp_w, tp_b, dirL, dirR, bias_l, bias_r);
    q_build<<<dim3(2048, 2), 256, 0, stream>>>(idsL, idsR, Pp, bias_l, bias_r, q_g, q_b, Qbf);

    // ---- K/V projections + LN fused (V written transposed) ----
    gemm_ln<<<dim3(512, 2), 256, 0, stream>>>(visbf, kwbf, vwbf, k_b, v_b, kv_g, kv_b, Kbf, Vt);

    // ---- MFMA cross-attention v4b: side-split, (512,1) ----
    attn_wave<<<512, 512, 0, stream>>>(Qbf, Kbf, Vt, vis_mask, tau, Fbf);

    // ---- tied classifier logits into d_out+1 (64x256 blocks, 16 MFMA/wave/step) ----
    gemm_bf<<<dim3(128, 2, 2), 256, 0, stream>>>(Fbf, embbf, cls_b, out + 1, 256, 512,
                                                 2097152, 4194304);

    // ---- SGM agreement loss (atomic-free two-stage reduction) ----
    loss_pair<<<2040, 256, 0, stream>>>(out + 1, tgt_mask, partials);
    loss_final<<<1, 256, 0, stream>>>(tgt_mask, partials, out);
}

// Round 12
// 319.376 us; speedup vs baseline: 1.0652x; 1.0652x over previous
//
#include <hip/hip_runtime.h>

typedef __attribute__((ext_vector_type(8))) short short8;
typedef __attribute__((ext_vector_type(4))) short short4v;
typedef __attribute__((ext_vector_type(4))) float f32x4;

__device__ __forceinline__ short f2bf(float x) {
    union { float f; unsigned u; } c; c.f = x;
    unsigned u = c.u;
    u += 0x7fffu + ((u >> 16) & 1u);
    return (short)(u >> 16);
}

// ---------------------------------------------------------------------------
// combined small converts (float4 counts): emb_w 32768, k_w 16384, v_w 16384
__global__ __launch_bounds__(256) void cvt3(const float* __restrict__ emb, const float* __restrict__ kw,
                                            const float* __restrict__ vw,
                                            short* __restrict__ de, short* __restrict__ dk, short* __restrict__ dv) {
    int i = blockIdx.x * 256 + threadIdx.x;   // 0..65535
    const float* s; short* d; int off;
    if (i < 32768) { s = emb; d = de; off = i; }
    else if (i < 49152) { s = kw; d = dk; off = i - 32768; }
    else { s = vw; d = dv; off = i - 49152; }
    float4 v = ((const float4*)s)[off];
    short4 o;
    o.x = f2bf(v.x); o.y = f2bf(v.y); o.z = f2bf(v.z); o.w = f2bf(v.w);
    ((short4*)d)[off] = o;
}

// ---------------------------------------------------------------------------
// Fold conv into W_fold^T; blockIdx.y selects side. (coalesced: ci=block, j=thread)
__global__ void build_wfold(const float* __restrict__ cl, const float* __restrict__ cr,
                            float* __restrict__ wfT) {
    const float* conv_w = blockIdx.y ? cr : cl;
    float* o = wfT + (long)blockIdx.y * 327680;
    const int ci = blockIdx.x;
    const int j = threadIdx.x;
    float acc[5] = {0.f, 0.f, 0.f, 0.f, 0.f};
#pragma unroll
    for (int i = 0; i < 5; ++i) {
        int flat = i * 256 + j;
        int c = flat / 5;
        int s = flat % 5;
#pragma unroll
        for (int k = 0; k < 3; ++k) {
            int si = s + k - 1;
            if (si >= 0 && si < 5) acc[si] += conv_w[(c * 256 + ci) * 3 + k];
        }
    }
#pragma unroll
    for (int si = 0; si < 5; ++si)
        o[(si * 256 + ci) * 256 + j] = acc[si] * 0.2f;
}

// ---------------------------------------------------------------------------
// fp32 tiled GEMM (small P-build path): C[row,col]=sum A[row,k]W[col,k]
template <bool BIAS>
__global__ __launch_bounds__(256) void gemm64(const float* __restrict__ A,
                                              const float* __restrict__ W,
                                              const float* __restrict__ bias,
                                              float* __restrict__ C,
                                              int K, int ldC,
                                              long sliceA, long sliceW, long sliceC) {
    A += (long)blockIdx.z * sliceA;
    W += (long)blockIdx.z * sliceW;
    C += (long)blockIdx.z * sliceC;
    const int row0 = blockIdx.x * 64;
    const int col0 = blockIdx.y * 64;
    __shared__ float As[32][68];
    __shared__ float Ws[32][68];
    const int t = threadIdx.x;
    const int tx = t & 15;
    const int ty = t >> 4;
    float acc[4][4] = {};
    for (int kk = 0; kk < K; kk += 32) {
#pragma unroll
        for (int e = 0; e < 8; ++e) {
            int f = t + 256 * e;
            int r = f >> 5, kc = f & 31;
            As[kc][r] = A[(long)(row0 + r) * K + kk + kc];
            Ws[kc][r] = W[(long)(col0 + r) * K + kk + kc];
        }
        __syncthreads();
#pragma unroll
        for (int kc = 0; kc < 32; ++kc) {
            float4 a4 = *(const float4*)&As[kc][ty * 4];
            float4 w4 = *(const float4*)&Ws[kc][tx * 4];
            float av[4] = {a4.x, a4.y, a4.z, a4.w};
            float wv[4] = {w4.x, w4.y, w4.z, w4.w};
#pragma unroll
            for (int i = 0; i < 4; ++i)
#pragma unroll
                for (int jj = 0; jj < 4; ++jj)
                    acc[i][jj] += av[i] * wv[jj];
        }
        __syncthreads();
    }
#pragma unroll
    for (int r = 0; r < 4; ++r) {
        int row = row0 + ty * 4 + r;
#pragma unroll
        for (int c = 0; c < 4; ++c) {
            int col = col0 + tx * 4 + c;
            float v = acc[r][c];
            if (BIAS) v += bias[col];
            C[(long)row * ldC + col] = v;
        }
    }
}

// ---------------------------------------------------------------------------
// bf16 MFMA GEMM (classifier): C = A.W^T + bias, fp32 out.
// ROUND-12: reverted verbatim to the round-8/10 proven 64x64-block version.
// Round-11's 64x256-block restructure regressed 325->340us: only 512 blocks
// = 2/CU co-resident could not hide the 5-load staging latency (the 2048
// small blocks give ~8 blocks/CU of TLP). Block-level parallelism beats
// per-wave MFMA density at these sizes.
__global__ __launch_bounds__(256) void gemm_bf(const short* __restrict__ A,
                                               const short* __restrict__ W,
                                               const float* __restrict__ bias,
                                               float* __restrict__ Cf,
                                               int K, int ldC,
                                               long sliceA, long sliceC) {
    A += (long)blockIdx.z * sliceA;
    const int row0 = blockIdx.x * 64, col0 = blockIdx.y * 64;
    __shared__ short As[64 * 40];
    __shared__ short Ws[64 * 40];
    const int t = threadIdx.x;
    const int wid = t >> 6, lane = t & 63, sub = lane & 15, quad = lane >> 4;
    const int wy = wid >> 1, wx = wid & 1;
    const int srow = t >> 2, sseg = t & 3;
    f32x4 acc00 = {0.f, 0.f, 0.f, 0.f}, acc01 = acc00, acc10 = acc00, acc11 = acc00;
    for (int kk = 0; kk < K; kk += 32) {
        *(short8*)&As[srow * 40 + sseg * 8] = *(const short8*)&A[(long)(row0 + srow) * K + kk + sseg * 8];
        *(short8*)&Ws[srow * 40 + sseg * 8] = *(const short8*)&W[(long)(col0 + srow) * K + kk + sseg * 8];
        __syncthreads();
        short8 a0 = *(const short8*)&As[(wy * 32 + sub) * 40 + quad * 8];
        short8 a1 = *(const short8*)&As[(wy * 32 + 16 + sub) * 40 + quad * 8];
        short8 b0 = *(const short8*)&Ws[(wx * 32 + sub) * 40 + quad * 8];
        short8 b1 = *(const short8*)&Ws[(wx * 32 + 16 + sub) * 40 + quad * 8];
        acc00 = __builtin_amdgcn_mfma_f32_16x16x32_bf16(a0, b0, acc00, 0, 0, 0);
        acc01 = __builtin_amdgcn_mfma_f32_16x16x32_bf16(a0, b1, acc01, 0, 0, 0);
        acc10 = __builtin_amdgcn_mfma_f32_16x16x32_bf16(a1, b0, acc10, 0, 0, 0);
        acc11 = __builtin_amdgcn_mfma_f32_16x16x32_bf16(a1, b1, acc11, 0, 0, 0);
        __syncthreads();
    }
    Cf += (long)blockIdx.z * sliceC;
#pragma unroll
    for (int i = 0; i < 2; ++i)
#pragma unroll
        for (int j = 0; j < 2; ++j) {
            f32x4 a = (i == 0) ? (j == 0 ? acc00 : acc01) : (j == 0 ? acc10 : acc11);
#pragma unroll
            for (int r = 0; r < 4; ++r) {
                int row = row0 + wy * 32 + i * 16 + quad * 4 + r;
                int col = col0 + wx * 32 + j * 16 + sub;
                Cf[(long)row * ldC + col] = a[r] + bias[col];
            }
        }
}

// ---------------------------------------------------------------------------
// K/V projection + bias + row LayerNorm fused; V written transposed into Vt.
// ROUND-12: cvt_bf16 fused into A-staging — reads vis_tokens fp32 directly
// and converts with the same f2bf (bit-identical LDS contents; visbf and its
// 50MB of convert traffic + one launch eliminated).
__global__ __launch_bounds__(256) void gemm_ln(const float* __restrict__ Af,
                                               const short* __restrict__ kwbf, const short* __restrict__ vwbf,
                                               const float* __restrict__ k_b, const float* __restrict__ v_b,
                                               const float* __restrict__ gamma, const float* __restrict__ beta,
                                               short* __restrict__ Kout, short* __restrict__ Vt) {
    const bool isV = blockIdx.y != 0;
    const short* W = isV ? vwbf : kwbf;
    const float* bias = isV ? v_b : k_b;
    const int row0 = blockIdx.x * 64;
    __shared__ short As[64 * 40];
    __shared__ short Ws[256 * 40];
    __shared__ float s_mu[64 * 4];
    __shared__ float s_sq[64 * 4];
    __shared__ float s_mv[64 * 2];
    const int t = threadIdx.x;
    const int wid = t >> 6, lane = t & 63, sub = lane & 15, quad = lane >> 4;
    f32x4 acc[4][4];
#pragma unroll
    for (int mi = 0; mi < 4; ++mi)
#pragma unroll
        for (int ni = 0; ni < 4; ++ni) acc[mi][ni] = (f32x4){0.f, 0.f, 0.f, 0.f};

    const int sr = t >> 2, sseg = t & 3;
    for (int kk = 0; kk < 256; kk += 32) {
        {   // fp32 load + inline f2bf convert (replaces cvt_bf16 kernel)
            const float* arow = &Af[(long)(row0 + sr) * 256 + kk + sseg * 8];
            float4 f0 = *(const float4*)&arow[0];
            float4 f1 = *(const float4*)&arow[4];
            short8 s8;
            s8[0] = f2bf(f0.x); s8[1] = f2bf(f0.y); s8[2] = f2bf(f0.z); s8[3] = f2bf(f0.w);
            s8[4] = f2bf(f1.x); s8[5] = f2bf(f1.y); s8[6] = f2bf(f1.z); s8[7] = f2bf(f1.w);
            *(short8*)&As[sr * 40 + sseg * 8] = s8;
        }
#pragma unroll
        for (int i = 0; i < 4; ++i) {
            int r = i * 64 + sr;
            *(short8*)&Ws[r * 40 + sseg * 8] = *(const short8*)&W[(long)r * 256 + kk + sseg * 8];
        }
        __syncthreads();
        short8 a[4], b[4];
#pragma unroll
        for (int mi = 0; mi < 4; ++mi) a[mi] = *(const short8*)&As[(mi * 16 + sub) * 40 + quad * 8];
#pragma unroll
        for (int ni = 0; ni < 4; ++ni) b[ni] = *(const short8*)&Ws[(wid * 64 + ni * 16 + sub) * 40 + quad * 8];
#pragma unroll
        for (int mi = 0; mi < 4; ++mi)
#pragma unroll
            for (int ni = 0; ni < 4; ++ni)
                acc[mi][ni] = __builtin_amdgcn_mfma_f32_16x16x32_bf16(a[mi], b[ni], acc[mi][ni], 0, 0, 0);
        __syncthreads();
    }
#pragma unroll
    for (int ni = 0; ni < 4; ++ni) {
        float bv = bias[wid * 64 + ni * 16 + sub];
#pragma unroll
        for (int mi = 0; mi < 4; ++mi)
#pragma unroll
            for (int r = 0; r < 4; ++r) acc[mi][ni][r] += bv;
    }
#pragma unroll
    for (int mi = 0; mi < 4; ++mi) {
#pragma unroll
        for (int r = 0; r < 4; ++r) {
            float s = 0.f, q2 = 0.f;
#pragma unroll
            for (int ni = 0; ni < 4; ++ni) {
                float v = acc[mi][ni][r];
                s += v; q2 += v * v;
            }
#pragma unroll
            for (int off = 8; off; off >>= 1) {
                s += __shfl_xor(s, off, 16);
                q2 += __shfl_xor(q2, off, 16);
            }
            if (sub == 0) {
                int row = mi * 16 + quad * 4 + r;
                s_mu[row * 4 + wid] = s;
                s_sq[row * 4 + wid] = q2;
            }
        }
    }
    __syncthreads();
    if (t < 64) {
        float s = s_mu[t * 4] + s_mu[t * 4 + 1] + s_mu[t * 4 + 2] + s_mu[t * 4 + 3];
        float q2 = s_sq[t * 4] + s_sq[t * 4 + 1] + s_sq[t * 4 + 2] + s_sq[t * 4 + 3];
        float mean = s * (1.0f / 256.0f);
        float var = q2 * (1.0f / 256.0f) - mean * mean;
        s_mv[t * 2] = mean;
        s_mv[t * 2 + 1] = rsqrtf(var + 1e-5f);
    }
    __syncthreads();
#pragma unroll
    for (int ni = 0; ni < 4; ++ni) {
        int col = wid * 64 + ni * 16 + sub;
        float g = gamma[col], bb = beta[col];
        if (!isV) {
#pragma unroll
            for (int mi = 0; mi < 4; ++mi)
#pragma unroll
                for (int r = 0; r < 4; ++r) {
                    int row = mi * 16 + quad * 4 + r;
                    float v = (acc[mi][ni][r] - s_mv[row * 2]) * s_mv[row * 2 + 1] * g + bb;
                    Kout[(long)(row0 + row) * 256 + col] = f2bf(v);
                }
        } else {
            int h = col >> 5, dh = col & 31;
#pragma unroll
            for (int mi = 0; mi < 4; ++mi) {
                int rowb = row0 + mi * 16 + quad * 4;
                short4 o;
#pragma unroll
                for (int r = 0; r < 4; ++r) {
                    int row = mi * 16 + quad * 4 + r;
                    float v = (acc[mi][ni][r] - s_mv[row * 2]) * s_mv[row * 2 + 1] * g + bb;
                    ((short*)&o)[r] = f2bf(v);
                }
                int gb = rowb >> 10, n = rowb & 1023;
                *(short4*)&Vt[((long)(gb * 8 + h) * 32 + dh) * 1024 + n] = o;
            }
        }
    }
}

// ---------------------------------------------------------------------------
// bias_dir: wave-per-8-outputs, coalesced j sweep + shuffle reduce.
__global__ __launch_bounds__(256) void bias_dir_kernel(const float* __restrict__ tp, const float* __restrict__ tpb,
                                                       const float* __restrict__ dirL, const float* __restrict__ dirR,
                                                       float* __restrict__ biasL, float* __restrict__ biasR) {
    const float* dir = blockIdx.y ? dirR : dirL;
    float* outp = blockIdx.y ? biasR : biasL;
    __shared__ float sdir[256];
    sdir[threadIdx.x] = dir[threadIdx.x];
    __syncthreads();
    const int wid = threadIdx.x >> 6, lane = threadIdx.x & 63;
#pragma unroll
    for (int i = 0; i < 8; ++i) {
        const int d = blockIdx.x * 32 + wid * 8 + i;
        float p = 0.f;
#pragma unroll
        for (int jj = 0; jj < 4; ++jj)
            p += tp[d * 256 + jj * 64 + lane] * sdir[jj * 64 + lane];
#pragma unroll
        for (int off = 32; off; off >>= 1) p += __shfl_xor(p, off, 64);
        if (lane == 0) outp[d] = p + tpb[d];
    }
}

// ---------------------------------------------------------------------------
// Q build, wave-per-row: gather 5 P rows, + dir bias, LN, bf16 out.
__global__ __launch_bounds__(256) void q_build(const int* __restrict__ idsL, const int* __restrict__ idsR,
                                               const float* __restrict__ Pp,
                                               const float* __restrict__ biasL, const float* __restrict__ biasR,
                                               const float* __restrict__ qg, const float* __restrict__ qb,
                                               short* __restrict__ Qbf) {
    const int wid = threadIdx.x >> 6, lane = threadIdx.x & 63;
    const int bl = blockIdx.x * 4 + wid;
    const bool right = blockIdx.y != 0;
    const int* ids = right ? idsR : idsL;
    const float* P = right ? Pp + 655360 : Pp;
    const float* bias = right ? biasR : biasL;
    const int d0 = lane * 4;
    float4 acc = *(const float4*)&bias[d0];
#pragma unroll
    for (int s = 0; s < 5; ++s) {
        int tok = ids[bl * 5 + s];
        float4 p = *(const float4*)&P[(long)(s * 512 + tok) * 256 + d0];
        acc.x += p.x; acc.y += p.y; acc.z += p.z; acc.w += p.w;
    }
    float sum = acc.x + acc.y + acc.z + acc.w;
    float sq = acc.x * acc.x + acc.y * acc.y + acc.z * acc.z + acc.w * acc.w;
#pragma unroll
    for (int off = 32; off; off >>= 1) {
        sum += __shfl_xor(sum, off, 64);
        sq += __shfl_xor(sq, off, 64);
    }
    float mean = sum * (1.0f / 256.0f);
    float var = sq * (1.0f / 256.0f) - mean * mean;
    float rstd = rsqrtf(var + 1e-5f);
    float4 g = *(const float4*)&qg[d0];
    float4 bb = *(const float4*)&qb[d0];
    short4 o;
    o.x = f2bf((acc.x - mean) * rstd * g.x + bb.x);
    o.y = f2bf((acc.y - mean) * rstd * g.y + bb.y);
    o.z = f2bf((acc.z - mean) * rstd * g.z + bb.z);
    o.w = f2bf((acc.w - mean) * rstd * g.w + bb.w);
    *(short4*)&Qbf[(right ? 2097152L : 0L) + (long)bl * 256 + d0] = o;
}

// ---------------------------------------------------------------------------
// One 32-n chunk for 64 l rows (4 Q-frags), ONE side (L/R split across
// waves). Mask from LDS (fp32, bit-exact), XOR-swizzled n4^(l&7). Math
// identical to the round-5-proven kernel, minus the R half.
__device__ __forceinline__ void proc_chunk(
    short8 ak0, short8 ak1, short4v v00, short4v v01, short4v v10, short4v v11,
    const float* mlds, int sub, int quad, float inv2,
    const short8 (&bq)[4],
    f32x4 (&o)[4][2], float (&ps)[4]) {
    short8 av0, av1;
#pragma unroll
    for (int j = 0; j < 4; ++j) {
        av0[j] = v00[j]; av0[4 + j] = v01[j];
        av1[j] = v10[j]; av1[4 + j] = v11[j];
    }
    const int sw = (quad ^ (sub & 7)) << 2;
#pragma unroll
    for (int lt = 0; lt < 4; ++lt) {
        const int mi = ((lt * 16 + sub) << 5) + sw;
        float4 mk0 = *(const float4*)&mlds[mi];
        float4 mk1 = *(const float4*)&mlds[mi ^ 16];
        float m0x = mk0.x * inv2, m0y = mk0.y * inv2, m0z = mk0.z * inv2, m0w = mk0.w * inv2;
        float m1x = mk1.x * inv2, m1y = mk1.y * inv2, m1z = mk1.z * inv2, m1w = mk1.w * inv2;
        f32x4 c0 = {0.f, 0.f, 0.f, 0.f}, c1 = c0;
        c0 = __builtin_amdgcn_mfma_f32_16x16x32_bf16(ak0, bq[lt], c0, 0, 0, 0);
        c1 = __builtin_amdgcn_mfma_f32_16x16x32_bf16(ak1, bq[lt], c1, 0, 0, 0);
        float p0 = __builtin_amdgcn_exp2f(c0[0] * m0x);
        float p1 = __builtin_amdgcn_exp2f(c0[1] * m0y);
        float p2 = __builtin_amdgcn_exp2f(c0[2] * m0z);
        float p3 = __builtin_amdgcn_exp2f(c0[3] * m0w);
        float p4 = __builtin_amdgcn_exp2f(c1[0] * m1x);
        float p5 = __builtin_amdgcn_exp2f(c1[1] * m1y);
        float p6 = __builtin_amdgcn_exp2f(c1[2] * m1z);
        float p7 = __builtin_amdgcn_exp2f(c1[3] * m1w);
        ps[lt] += ((p0 + p1) + (p2 + p3)) + ((p4 + p5) + (p6 + p7));
        short8 p8;
        p8[0] = f2bf(p0); p8[1] = f2bf(p1); p8[2] = f2bf(p2); p8[3] = f2bf(p3);
        p8[4] = f2bf(p4); p8[5] = f2bf(p5); p8[6] = f2bf(p6); p8[7] = f2bf(p7);
        o[lt][0] = __builtin_amdgcn_mfma_f32_16x16x32_bf16(av0, p8, o[lt][0], 0, 0, 0);
        o[lt][1] = __builtin_amdgcn_mfma_f32_16x16x32_bf16(av1, p8, o[lt][1], 0, 0, 0);
    }
}

// ---------------------------------------------------------------------------
// MFMA cross-attention v4b: side-split, launch_bounds(512,1).
// Measured round-10/11: VGPR 112, no spill, FETCH 37.8MB, dur ~73us at ~20%
// occupancy — barrier-pipeline-bound, kept as-is.
__global__ __launch_bounds__(512, 1) void attn_wave(const short* __restrict__ Qbf,
                                                    const short* __restrict__ Kbf,
                                                    const short* __restrict__ Vt,
                                                    const float* __restrict__ vis_mask,
                                                    const float* __restrict__ tau_p,
                                                    short* __restrict__ Fbf) {
    const int t = threadIdx.x;
    const int wid = t >> 6, lane = t & 63, sub = lane & 15, quad = lane >> 4;
    // bijective XCD swizzle over 512 blocks (64 per XCD)
    const int gb = ((blockIdx.x & 7) << 6) | (blockIdx.x >> 3);
    const int b = gb >> 4;            // 0..31
    const int lb = (gb >> 2) & 3;     // 0..3  (64-l block)
    const int hp = gb & 3;            // 0..3  (h pair)
    const int wh = wid >> 2;          // h in pair
    const int side = (wid >> 1) & 1;  // 0 = L, 1 = R
    const int nh = wid & 1;           // n-half
    const int h = hp * 2 + wh;        // 0..7
    const int l0 = lb * 64;
    float tau = fminf(fmaxf(tau_p[0], 0.25f), 4.0f);
    const float inv2 = 1.4426950408889634f / (5.656854249492381f * tau);

    // mask LDS: [2 buf][2 nh][64 l][8 n4'][4] floats = 32 KB, n4' = n4^(l&7)
    __shared__ float mbuf[2 * 4096];
    // combine buffer: pair p = (wh,side), payload o(32)+ps(4) @ stride 40
    __shared__ float red[4][64][40];

    // staging precompute: thread t owns 16B slots s0=2t, s1=2t+1
    const int s0 = t * 2;
    const int l_s = (s0 >> 3) & 63, nh_s = s0 >> 9;
    const int n4a = s0 & 7, n4b = n4a + 1;
    const float* mrow0 = vis_mask + (long)(b * 256 + l0 + l_s) * 1024 + nh_s * 512 + 4 * (n4a ^ (l_s & 7));
    const float* mrow1 = vis_mask + (long)(b * 256 + l0 + l_s) * 1024 + nh_s * 512 + 4 * (n4b ^ (l_s & 7));
    float* mdst0 = mbuf + nh_s * 2048 + l_s * 32 + n4a * 4;
    float* mdst1 = mbuf + nh_s * 2048 + l_s * 32 + n4b * 4;

    // Q B-frags for 4 l-tiles, this wave's side only
    const short* Qside = Qbf + (side ? 2097152L : 0L);
    short8 bq[4];
#pragma unroll
    for (int lt = 0; lt < 4; ++lt) {
        const long qoff = (long)(b * 256 + l0 + lt * 16 + sub) * 256 + h * 32 + quad * 8;
        bq[lt] = *(const short8*)&Qside[qoff];
    }

    const short* Kb = Kbf + (long)b * 262144 + h * 32;            // + n*256 + quad*8
    const short* Vb = Vt + (long)(b * 8 + h) * 32768;             // Vt[dh][n]
    const float* mld = mbuf + nh * 2048;                          // this wave's nh half

    f32x4 o[4][2];
    float ps[4];
#pragma unroll
    for (int lt = 0; lt < 4; ++lt) {
        o[lt][0] = (f32x4){0.f, 0.f, 0.f, 0.f}; o[lt][1] = o[lt][0];
        ps[lt] = 0.f;
    }

    const int nbeg = nh << 9;   // n-half [nbeg, nbeg+512)

#define LOADK(A0, A1, N)                                                      \
    A0 = *(const short8*)&Kb[(long)((N) + sub) * 256 + quad * 8];             \
    A1 = *(const short8*)&Kb[(long)((N) + 16 + sub) * 256 + quad * 8];
#define LOADV(W00, W01, W10, W11, N)                                          \
    W00 = *(const short4v*)&Vb[(long)sub * 1024 + (N) + quad * 4];            \
    W01 = *(const short4v*)&Vb[(long)sub * 1024 + (N) + 16 + quad * 4];       \
    W10 = *(const short4v*)&Vb[(long)(16 + sub) * 1024 + (N) + quad * 4];     \
    W11 = *(const short4v*)&Vb[(long)(16 + sub) * 1024 + (N) + 16 + quad * 4];

    short8 ak0A, ak1A, ak0B, ak1B;
    short4v v00A, v01A, v10A, v11A, v00B, v01B, v10B, v11B;
    float4 mr0, mr1;

    // prologue: stage mask chunk 0 into buf0, prefetch K/V chunk 0
    mr0 = *(const float4*)&mrow0[0];
    mr1 = *(const float4*)&mrow1[0];
    *(float4*)&mdst0[0] = mr0;
    *(float4*)&mdst1[0] = mr1;
    LOADK(ak0A, ak1A, nbeg)
    LOADV(v00A, v01A, v10A, v11A, nbeg)
    __syncthreads();

#pragma unroll 1
    for (int j = 0; j < 8; ++j) {
        const int n0 = nbeg + j * 64;
        // ---- chunk 2j (mask buf0) ----
        LOADK(ak0B, ak1B, n0 + 32)
        LOADV(v00B, v01B, v10B, v11B, n0 + 32)
        {   // load mask chunk 2j+1 (always valid) into regs
            const int nrel = j * 64 + 32;
            mr0 = *(const float4*)&mrow0[nrel];
            mr1 = *(const float4*)&mrow1[nrel];
        }
        proc_chunk(ak0A, ak1A, v00A, v01A, v10A, v11A, mld, sub, quad, inv2,
                   bq, o, ps);
        *(float4*)&mdst0[4096] = mr0;       // write chunk 2j+1 -> buf1
        *(float4*)&mdst1[4096] = mr1;
        __syncthreads();
        // ---- chunk 2j+1 (mask buf1) ----
        const int nx = (j < 7) ? n0 + 64 : nbeg;     // last prefetch = dummy (hot)
        LOADK(ak0A, ak1A, nx)
        LOADV(v00A, v01A, v10A, v11A, nx)
        {   // load mask chunk 2j+2 (dummy reload of chunk0 at j=7)
            const int nrel = (j < 7) ? j * 64 + 64 : 0;
            mr0 = *(const float4*)&mrow0[nrel];
            mr1 = *(const float4*)&mrow1[nrel];
        }
        proc_chunk(ak0B, ak1B, v00B, v01B, v10B, v11B, mld + 4096, sub, quad, inv2,
                   bq, o, ps);
        *(float4*)&mdst0[0] = mr0;          // write chunk 2j+2 -> buf0 (dummy at j=7)
        *(float4*)&mdst1[0] = mr1;
        __syncthreads();
    }
#undef LOADK
#undef LOADV

    // full row-sums per l-tile for l = sub (combine the 4 quads)
#pragma unroll
    for (int lt = 0; lt < 4; ++lt) {
        ps[lt] += __shfl_xor(ps[lt], 16, 64);
        ps[lt] += __shfl_xor(ps[lt], 32, 64);
    }

    // cross n-half combine within (wh, side) pair: nh==1 publishes,
    // one barrier, nh==0 adds. layout per lane: [0..31]=o, [32..35]=ps.
    const int pr = wid >> 1;   // pair index = wh*2+side
    if (nh == 1) {
        float* p = &red[pr][lane][0];
#pragma unroll
        for (int lt = 0; lt < 4; ++lt) {
            *(f32x4*)(p + lt * 8) = o[lt][0];
            *(f32x4*)(p + lt * 8 + 4) = o[lt][1];
            p[32 + lt] = ps[lt];
        }
    }
    __syncthreads();
    if (nh == 1) return;
    {
        const float* p = &red[pr][lane][0];
#pragma unroll
        for (int lt = 0; lt < 4; ++lt) {
            f32x4 e0 = *(const f32x4*)(p + lt * 8);
            f32x4 e1 = *(const f32x4*)(p + lt * 8 + 4);
#pragma unroll
            for (int q = 0; q < 4; ++q) {
                o[lt][0][q] += e0[q];
                o[lt][1][q] += e1[q];
            }
            ps[lt] += p[32 + lt];
        }
    }

    // O^T[4*quad+r (+16)][l] -> F[b,l][h*32 + 4*quad + r (+16)]
    short* Fside = Fbf + (side ? 2097152L : 0L);
#pragma unroll
    for (int lt = 0; lt < 4; ++lt) {
        const long fo = (long)(b * 256 + l0 + lt * 16 + sub) * 256 + h * 32 + quad * 4;
        const float rS = 1.0f / ps[lt];
        short4v s0v, s1v;
#pragma unroll
        for (int r = 0; r < 4; ++r) { s0v[r] = f2bf(o[lt][0][r] * rS); s1v[r] = f2bf(o[lt][1][r] * rS); }
        *(short4v*)&Fside[fo] = s0v;
        *(short4v*)&Fside[fo + 16] = s1v;
    }
}

// ---------------------------------------------------------------------------
// Loss: wave per (b,l) pair; block-level reduce, one plain store per block.
__global__ __launch_bounds__(256) void loss_pair(const float* __restrict__ logits,
                                                 const float* __restrict__ tgt_mask,
                                                 float* __restrict__ partials) {
    const int wid = threadIdx.x >> 6, lane = threadIdx.x & 63;
    const int pid = blockIdx.x * 4 + wid;   // 0..8159
    const int b = pid / 255, l = pid - b * 255;
    const float* ll = logits + (long)(b * 256 + l) * 512;
    const float* lr = logits + 4194304 + (long)(b * 256 + l + 1) * 512;
    float a[8], c[8];
#pragma unroll
    for (int j = 0; j < 8; ++j) {
        a[j] = ll[lane + 64 * j] * 0.5f;
        c[j] = lr[lane + 64 * j] * 0.5f;
    }
    float ml = -1e30f, mr = -1e30f;
#pragma unroll
    for (int j = 0; j < 8; ++j) { ml = fmaxf(ml, a[j]); mr = fmaxf(mr, c[j]); }
#pragma unroll
    for (int off = 32; off; off >>= 1) {
        ml = fmaxf(ml, __shfl_xor(ml, off, 64));
        mr = fmaxf(mr, __shfl_xor(mr, off, 64));
    }
    float sl = 0.f, sr = 0.f;
#pragma unroll
    for (int j = 0; j < 8; ++j) {
        a[j] = __expf(a[j] - ml); sl += a[j];
        c[j] = __expf(c[j] - mr); sr += c[j];
    }
#pragma unroll
    for (int off = 32; off; off >>= 1) {
        sl += __shfl_xor(sl, off, 64);
        sr += __shfl_xor(sr, off, 64);
    }
    float rl = 1.0f / sl, rr = 1.0f / sr;
    float sq = 0.f;
#pragma unroll
    for (int j = 0; j < 8; ++j) {
        float d = a[j] * rl - c[j] * rr;
        sq += d * d;
    }
#pragma unroll
    for (int off = 32; off; off >>= 1) sq += __shfl_xor(sq, off, 64);

    __shared__ float sred[4];
    if (lane == 0) sred[wid] = sq * tgt_mask[b * 256 + l];
    __syncthreads();
    if (threadIdx.x == 0)
        partials[blockIdx.x] = (sred[0] + sred[1]) + (sred[2] + sred[3]);
}

__global__ __launch_bounds__(256) void loss_final(const float* __restrict__ tgt_mask,
                                                  const float* __restrict__ partials,
                                                  float* __restrict__ outp) {
    const int t = threadIdx.x;
    float s = 0.f, acc = 0.f;
    for (int i = t; i < 32 * 255; i += 256) {
        int b = i / 255, l = i % 255;
        s += tgt_mask[b * 256 + l];
    }
    for (int i = t; i < 2040; i += 256) acc += partials[i];
    __shared__ float red[256];
    __shared__ float reda[256];
    red[t] = s;
    reda[t] = acc;
    __syncthreads();
    for (int st = 128; st; st >>= 1) {
        if (t < st) { red[t] += red[t + st]; reda[t] += reda[t + st]; }
        __syncthreads();
    }
    if (t == 0) outp[0] = 0.1f * reda[0] / fmaxf(red[0], 1.0f);
}

// ---------------------------------------------------------------------------
extern "C" void kernel_launch(void* const* d_in, const int* in_sizes, int n_in,
                              void* d_out, int out_size, void* d_ws, size_t ws_size,
                              hipStream_t stream) {
    const float* vis_tokens = (const float*)d_in[0];
    const int* idsL = (const int*)d_in[1];
    const int* idsR = (const int*)d_in[2];
    const float* tgt_mask = (const float*)d_in[4];
    const float* vis_mask = (const float*)d_in[5];
    const float* emb_w = (const float*)d_in[6];
    const float* dirL = (const float*)d_in[7];
    const float* dirR = (const float*)d_in[8];
    const float* tp_w = (const float*)d_in[9];
    const float* tp_b = (const float*)d_in[10];
    const float* q_g = (const float*)d_in[11];
    const float* q_b = (const float*)d_in[12];
    const float* k_w = (const float*)d_in[13];
    const float* k_b = (const float*)d_in[14];
    const float* v_w = (const float*)d_in[15];
    const float* v_b = (const float*)d_in[16];
    const float* kv_g = (const float*)d_in[17];
    const float* kv_b = (const float*)d_in[18];
    const float* tau = (const float*)d_in[19];
    const float* cls_b = (const float*)d_in[20];
    const float* conv_l = (const float*)d_in[21];
    const float* conv_r = (const float*)d_in[22];
    float* out = (float*)d_out;

    // ---- workspace layout (visbf slot retired; layout kept stable) ----
    short* sws = (short*)d_ws;
    short* embbf = sws + 8388608;               // 131,072
    short* kwbf  = embbf + 131072;              // 65,536
    short* vwbf  = kwbf + 65536;                // 65,536
    short* Kbf   = vwbf + 65536;                // 8,388,608
    short* Vt    = Kbf + 8388608;               // 8,388,608
    short* Qbf   = Vt + 8388608;                // 4,194,304 (L|R)
    short* Fbf   = Qbf + 4194304;               // 4,194,304 (L|R)
    float* wfT   = (float*)(Fbf + 4194304);     // 10 slices x 65536
    float* Ms    = wfT + 655360;                // 10 x 65536
    float* Pp    = Ms + 655360;                 // 10 x 131072
    float* bias_l = Pp + 1310720;
    float* bias_r = bias_l + 256;
    float* partials = bias_r + 256;             // 2040 floats

    // ---- weight converts (vis_tokens convert fused into gemm_ln) ----
    cvt3<<<256, 256, 0, stream>>>(emb_w, k_w, v_w, embbf, kwbf, vwbf);

    // ---- ctx path: wfold -> Ms -> P (fp32, small) ----
    build_wfold<<<dim3(256, 2), 256, 0, stream>>>(conv_l, conv_r, wfT);
    gemm64<false><<<dim3(4, 4, 10), 256, 0, stream>>>(tp_w, wfT, nullptr, Ms, 256, 256, 0, 65536, 65536);
    gemm64<false><<<dim3(8, 4, 10), 256, 0, stream>>>(emb_w, Ms, nullptr, Pp, 256, 256, 0, 65536, 131072);
    bias_dir_kernel<<<dim3(8, 2), 256, 0, stream>>>(tp_w, tp_b, dirL, dirR, bias_l, bias_r);
    q_build<<<dim3(2048, 2), 256, 0, stream>>>(idsL, idsR, Pp, bias_l, bias_r, q_g, q_b, Qbf);

    // ---- K/V projections + LN fused (fp32 A read + inline cvt) ----
    gemm_ln<<<dim3(512, 2), 256, 0, stream>>>(vis_tokens, kwbf, vwbf, k_b, v_b, kv_g, kv_b, Kbf, Vt);

    // ---- MFMA cross-attention v4b: side-split, (512,1) ----
    attn_wave<<<512, 512, 0, stream>>>(Qbf, Kbf, Vt, vis_mask, tau, Fbf);

    // ---- tied classifier logits into d_out+1 (proven 64x64-block version) ----
    gemm_bf<<<dim3(128, 8, 2), 256, 0, stream>>>(Fbf, embbf, cls_b, out + 1, 256, 512,
                                                 2097152, 4194304);

    // ---- SGM agreement loss (atomic-free two-stage reduction) ----
    loss_pair<<<2040, 256, 0, stream>>>(out + 1, tgt_mask, partials);
    loss_final<<<1, 256, 0, stream>>>(tgt_mask, partials, out);
}

// Round 13
// 311.479 us; speedup vs baseline: 1.0922x; 1.0254x over previous
//
#include <hip/hip_runtime.h>

typedef __attribute__((ext_vector_type(8))) short short8;
typedef __attribute__((ext_vector_type(4))) short short4v;
typedef __attribute__((ext_vector_type(4))) float f32x4;

__device__ __forceinline__ short f2bf(float x) {
    union { float f; unsigned u; } c; c.f = x;
    unsigned u = c.u;
    u += 0x7fffu + ((u >> 16) & 1u);
    return (short)(u >> 16);
}

// ---------------------------------------------------------------------------
// Merged prep kernel (round-13): three independent preprocessing roles that
// previously ran as 3 serial partial-fill launches (cvt3 256 blocks = 1/CU,
// wfold 512, bias_dir 16 blocks = 6% of CUs). One 784-block launch fills the
// machine and saves 2 launch gaps. Each role body is verbatim-proven code.
//   blocks [0,256)   : cvt3  — emb/k/v fp32->bf16
//   blocks [256,768) : build_wfold
//   blocks [768,784) : bias_dir
__global__ __launch_bounds__(256) void prep(const float* __restrict__ emb, const float* __restrict__ kw,
                                            const float* __restrict__ vw,
                                            short* __restrict__ de, short* __restrict__ dk, short* __restrict__ dv,
                                            const float* __restrict__ cl, const float* __restrict__ cr,
                                            float* __restrict__ wfT,
                                            const float* __restrict__ tp, const float* __restrict__ tpb,
                                            const float* __restrict__ dirL, const float* __restrict__ dirR,
                                            float* __restrict__ biasL, float* __restrict__ biasR) {
    const int bid = blockIdx.x;
    if (bid < 256) {
        // ---- role: cvt3 ----
        int i = bid * 256 + threadIdx.x;   // 0..65535
        const float* s; short* d; int off;
        if (i < 32768) { s = emb; d = de; off = i; }
        else if (i < 49152) { s = kw; d = dk; off = i - 32768; }
        else { s = vw; d = dv; off = i - 49152; }
        float4 v = ((const float4*)s)[off];
        short4 o;
        o.x = f2bf(v.x); o.y = f2bf(v.y); o.z = f2bf(v.z); o.w = f2bf(v.w);
        ((short4*)d)[off] = o;
    } else if (bid < 768) {
        // ---- role: build_wfold (ci=sub-block, j=thread; coalesced stores) ----
        const int idx = bid - 256;
        const int side = idx >> 8;
        const int ci = idx & 255;
        const float* conv_w = side ? cr : cl;
        float* o = wfT + (long)side * 327680;
        const int j = threadIdx.x;
        float acc[5] = {0.f, 0.f, 0.f, 0.f, 0.f};
#pragma unroll
        for (int i = 0; i < 5; ++i) {
            int flat = i * 256 + j;
            int c = flat / 5;
            int s = flat % 5;
#pragma unroll
            for (int k = 0; k < 3; ++k) {
                int si = s + k - 1;
                if (si >= 0 && si < 5) acc[si] += conv_w[(c * 256 + ci) * 3 + k];
            }
        }
#pragma unroll
        for (int si = 0; si < 5; ++si)
            o[(si * 256 + ci) * 256 + j] = acc[si] * 0.2f;
    } else {
        // ---- role: bias_dir (wave-per-8-outputs, coalesced + shuffle reduce) ----
        const int idx = bid - 768;
        const int side = idx >> 3;
        const int xb = idx & 7;
        const float* dir = side ? dirR : dirL;
        float* outp = side ? biasR : biasL;
        __shared__ float sdir[256];
        sdir[threadIdx.x] = dir[threadIdx.x];
        __syncthreads();
        const int wid = threadIdx.x >> 6, lane = threadIdx.x & 63;
#pragma unroll
        for (int i = 0; i < 8; ++i) {
            const int d = xb * 32 + wid * 8 + i;
            float p = 0.f;
#pragma unroll
            for (int jj = 0; jj < 4; ++jj)
                p += tp[d * 256 + jj * 64 + lane] * sdir[jj * 64 + lane];
#pragma unroll
            for (int off = 32; off; off >>= 1) p += __shfl_xor(p, off, 64);
            if (lane == 0) outp[d] = p + tpb[d];
        }
    }
}

// ---------------------------------------------------------------------------
// fp32 tiled GEMM (small P-build path): C[row,col]=sum A[row,k]W[col,k]
template <bool BIAS>
__global__ __launch_bounds__(256) void gemm64(const float* __restrict__ A,
                                              const float* __restrict__ W,
                                              const float* __restrict__ bias,
                                              float* __restrict__ C,
                                              int K, int ldC,
                                              long sliceA, long sliceW, long sliceC) {
    A += (long)blockIdx.z * sliceA;
    W += (long)blockIdx.z * sliceW;
    C += (long)blockIdx.z * sliceC;
    const int row0 = blockIdx.x * 64;
    const int col0 = blockIdx.y * 64;
    __shared__ float As[32][68];
    __shared__ float Ws[32][68];
    const int t = threadIdx.x;
    const int tx = t & 15;
    const int ty = t >> 4;
    float acc[4][4] = {};
    for (int kk = 0; kk < K; kk += 32) {
#pragma unroll
        for (int e = 0; e < 8; ++e) {
            int f = t + 256 * e;
            int r = f >> 5, kc = f & 31;
            As[kc][r] = A[(long)(row0 + r) * K + kk + kc];
            Ws[kc][r] = W[(long)(col0 + r) * K + kk + kc];
        }
        __syncthreads();
#pragma unroll
        for (int kc = 0; kc < 32; ++kc) {
            float4 a4 = *(const float4*)&As[kc][ty * 4];
            float4 w4 = *(const float4*)&Ws[kc][tx * 4];
            float av[4] = {a4.x, a4.y, a4.z, a4.w};
            float wv[4] = {w4.x, w4.y, w4.z, w4.w};
#pragma unroll
            for (int i = 0; i < 4; ++i)
#pragma unroll
                for (int jj = 0; jj < 4; ++jj)
                    acc[i][jj] += av[i] * wv[jj];
        }
        __syncthreads();
    }
#pragma unroll
    for (int r = 0; r < 4; ++r) {
        int row = row0 + ty * 4 + r;
#pragma unroll
        for (int c = 0; c < 4; ++c) {
            int col = col0 + tx * 4 + c;
            float v = acc[r][c];
            if (BIAS) v += bias[col];
            C[(long)row * ldC + col] = v;
        }
    }
}

// ---------------------------------------------------------------------------
// bf16 MFMA GEMM (classifier): C = A.W^T + bias, fp32 out.
// Proven 64x64-block version (2048 blocks = ~8/CU of TLP; the 64x256
// restructure regressed 325->340us in round 11).
__global__ __launch_bounds__(256) void gemm_bf(const short* __restrict__ A,
                                               const short* __restrict__ W,
                                               const float* __restrict__ bias,
                                               float* __restrict__ Cf,
                                               int K, int ldC,
                                               long sliceA, long sliceC) {
    A += (long)blockIdx.z * sliceA;
    const int row0 = blockIdx.x * 64, col0 = blockIdx.y * 64;
    __shared__ short As[64 * 40];
    __shared__ short Ws[64 * 40];
    const int t = threadIdx.x;
    const int wid = t >> 6, lane = t & 63, sub = lane & 15, quad = lane >> 4;
    const int wy = wid >> 1, wx = wid & 1;
    const int srow = t >> 2, sseg = t & 3;
    f32x4 acc00 = {0.f, 0.f, 0.f, 0.f}, acc01 = acc00, acc10 = acc00, acc11 = acc00;
    for (int kk = 0; kk < K; kk += 32) {
        *(short8*)&As[srow * 40 + sseg * 8] = *(const short8*)&A[(long)(row0 + srow) * K + kk + sseg * 8];
        *(short8*)&Ws[srow * 40 + sseg * 8] = *(const short8*)&W[(long)(col0 + srow) * K + kk + sseg * 8];
        __syncthreads();
        short8 a0 = *(const short8*)&As[(wy * 32 + sub) * 40 + quad * 8];
        short8 a1 = *(const short8*)&As[(wy * 32 + 16 + sub) * 40 + quad * 8];
        short8 b0 = *(const short8*)&Ws[(wx * 32 + sub) * 40 + quad * 8];
        short8 b1 = *(const short8*)&Ws[(wx * 32 + 16 + sub) * 40 + quad * 8];
        acc00 = __builtin_amdgcn_mfma_f32_16x16x32_bf16(a0, b0, acc00, 0, 0, 0);
        acc01 = __builtin_amdgcn_mfma_f32_16x16x32_bf16(a0, b1, acc01, 0, 0, 0);
        acc10 = __builtin_amdgcn_mfma_f32_16x16x32_bf16(a1, b0, acc10, 0, 0, 0);
        acc11 = __builtin_amdgcn_mfma_f32_16x16x32_bf16(a1, b1, acc11, 0, 0, 0);
        __syncthreads();
    }
    Cf += (long)blockIdx.z * sliceC;
#pragma unroll
    for (int i = 0; i < 2; ++i)
#pragma unroll
        for (int j = 0; j < 2; ++j) {
            f32x4 a = (i == 0) ? (j == 0 ? acc00 : acc01) : (j == 0 ? acc10 : acc11);
#pragma unroll
            for (int r = 0; r < 4; ++r) {
                int row = row0 + wy * 32 + i * 16 + quad * 4 + r;
                int col = col0 + wx * 32 + j * 16 + sub;
                Cf[(long)row * ldC + col] = a[r] + bias[col];
            }
        }
}

// ---------------------------------------------------------------------------
// K/V projection + bias + row LayerNorm fused; V written transposed into Vt.
// vis_tokens fp32 read + inline f2bf convert (cvt_bf16 kernel fused away).
__global__ __launch_bounds__(256) void gemm_ln(const float* __restrict__ Af,
                                               const short* __restrict__ kwbf, const short* __restrict__ vwbf,
                                               const float* __restrict__ k_b, const float* __restrict__ v_b,
                                               const float* __restrict__ gamma, const float* __restrict__ beta,
                                               short* __restrict__ Kout, short* __restrict__ Vt) {
    const bool isV = blockIdx.y != 0;
    const short* W = isV ? vwbf : kwbf;
    const float* bias = isV ? v_b : k_b;
    const int row0 = blockIdx.x * 64;
    __shared__ short As[64 * 40];
    __shared__ short Ws[256 * 40];
    __shared__ float s_mu[64 * 4];
    __shared__ float s_sq[64 * 4];
    __shared__ float s_mv[64 * 2];
    const int t = threadIdx.x;
    const int wid = t >> 6, lane = t & 63, sub = lane & 15, quad = lane >> 4;
    f32x4 acc[4][4];
#pragma unroll
    for (int mi = 0; mi < 4; ++mi)
#pragma unroll
        for (int ni = 0; ni < 4; ++ni) acc[mi][ni] = (f32x4){0.f, 0.f, 0.f, 0.f};

    const int sr = t >> 2, sseg = t & 3;
    for (int kk = 0; kk < 256; kk += 32) {
        {   // fp32 load + inline f2bf convert (replaces cvt_bf16 kernel)
            const float* arow = &Af[(long)(row0 + sr) * 256 + kk + sseg * 8];
            float4 f0 = *(const float4*)&arow[0];
            float4 f1 = *(const float4*)&arow[4];
            short8 s8;
            s8[0] = f2bf(f0.x); s8[1] = f2bf(f0.y); s8[2] = f2bf(f0.z); s8[3] = f2bf(f0.w);
            s8[4] = f2bf(f1.x); s8[5] = f2bf(f1.y); s8[6] = f2bf(f1.z); s8[7] = f2bf(f1.w);
            *(short8*)&As[sr * 40 + sseg * 8] = s8;
        }
#pragma unroll
        for (int i = 0; i < 4; ++i) {
            int r = i * 64 + sr;
            *(short8*)&Ws[r * 40 + sseg * 8] = *(const short8*)&W[(long)r * 256 + kk + sseg * 8];
        }
        __syncthreads();
        short8 a[4], b[4];
#pragma unroll
        for (int mi = 0; mi < 4; ++mi) a[mi] = *(const short8*)&As[(mi * 16 + sub) * 40 + quad * 8];
#pragma unroll
        for (int ni = 0; ni < 4; ++ni) b[ni] = *(const short8*)&Ws[(wid * 64 + ni * 16 + sub) * 40 + quad * 8];
#pragma unroll
        for (int mi = 0; mi < 4; ++mi)
#pragma unroll
            for (int ni = 0; ni < 4; ++ni)
                acc[mi][ni] = __builtin_amdgcn_mfma_f32_16x16x32_bf16(a[mi], b[ni], acc[mi][ni], 0, 0, 0);
        __syncthreads();
    }
#pragma unroll
    for (int ni = 0; ni < 4; ++ni) {
        float bv = bias[wid * 64 + ni * 16 + sub];
#pragma unroll
        for (int mi = 0; mi < 4; ++mi)
#pragma unroll
            for (int r = 0; r < 4; ++r) acc[mi][ni][r] += bv;
    }
#pragma unroll
    for (int mi = 0; mi < 4; ++mi) {
#pragma unroll
        for (int r = 0; r < 4; ++r) {
            float s = 0.f, q2 = 0.f;
#pragma unroll
            for (int ni = 0; ni < 4; ++ni) {
                float v = acc[mi][ni][r];
                s += v; q2 += v * v;
            }
#pragma unroll
            for (int off = 8; off; off >>= 1) {
                s += __shfl_xor(s, off, 16);
                q2 += __shfl_xor(q2, off, 16);
            }
            if (sub == 0) {
                int row = mi * 16 + quad * 4 + r;
                s_mu[row * 4 + wid] = s;
                s_sq[row * 4 + wid] = q2;
            }
        }
    }
    __syncthreads();
    if (t < 64) {
        float s = s_mu[t * 4] + s_mu[t * 4 + 1] + s_mu[t * 4 + 2] + s_mu[t * 4 + 3];
        float q2 = s_sq[t * 4] + s_sq[t * 4 + 1] + s_sq[t * 4 + 2] + s_sq[t * 4 + 3];
        float mean = s * (1.0f / 256.0f);
        float var = q2 * (1.0f / 256.0f) - mean * mean;
        s_mv[t * 2] = mean;
        s_mv[t * 2 + 1] = rsqrtf(var + 1e-5f);
    }
    __syncthreads();
#pragma unroll
    for (int ni = 0; ni < 4; ++ni) {
        int col = wid * 64 + ni * 16 + sub;
        float g = gamma[col], bb = beta[col];
        if (!isV) {
#pragma unroll
            for (int mi = 0; mi < 4; ++mi)
#pragma unroll
                for (int r = 0; r < 4; ++r) {
                    int row = mi * 16 + quad * 4 + r;
                    float v = (acc[mi][ni][r] - s_mv[row * 2]) * s_mv[row * 2 + 1] * g + bb;
                    Kout[(long)(row0 + row) * 256 + col] = f2bf(v);
                }
        } else {
            int h = col >> 5, dh = col & 31;
#pragma unroll
            for (int mi = 0; mi < 4; ++mi) {
                int rowb = row0 + mi * 16 + quad * 4;
                short4 o;
#pragma unroll
                for (int r = 0; r < 4; ++r) {
                    int row = mi * 16 + quad * 4 + r;
                    float v = (acc[mi][ni][r] - s_mv[row * 2]) * s_mv[row * 2 + 1] * g + bb;
                    ((short*)&o)[r] = f2bf(v);
                }
                int gb = rowb >> 10, n = rowb & 1023;
                *(short4*)&Vt[((long)(gb * 8 + h) * 32 + dh) * 1024 + n] = o;
            }
        }
    }
}

// ---------------------------------------------------------------------------
// Q build, wave-per-row: gather 5 P rows, + dir bias, LN, bf16 out.
__global__ __launch_bounds__(256) void q_build(const int* __restrict__ idsL, const int* __restrict__ idsR,
                                               const float* __restrict__ Pp,
                                               const float* __restrict__ biasL, const float* __restrict__ biasR,
                                               const float* __restrict__ qg, const float* __restrict__ qb,
                                               short* __restrict__ Qbf) {
    const int wid = threadIdx.x >> 6, lane = threadIdx.x & 63;
    const int bl = blockIdx.x * 4 + wid;
    const bool right = blockIdx.y != 0;
    const int* ids = right ? idsR : idsL;
    const float* P = right ? Pp + 655360 : Pp;
    const float* bias = right ? biasR : biasL;
    const int d0 = lane * 4;
    float4 acc = *(const float4*)&bias[d0];
#pragma unroll
    for (int s = 0; s < 5; ++s) {
        int tok = ids[bl * 5 + s];
        float4 p = *(const float4*)&P[(long)(s * 512 + tok) * 256 + d0];
        acc.x += p.x; acc.y += p.y; acc.z += p.z; acc.w += p.w;
    }
    float sum = acc.x + acc.y + acc.z + acc.w;
    float sq = acc.x * acc.x + acc.y * acc.y + acc.z * acc.z + acc.w * acc.w;
#pragma unroll
    for (int off = 32; off; off >>= 1) {
        sum += __shfl_xor(sum, off, 64);
        sq += __shfl_xor(sq, off, 64);
    }
    float mean = sum * (1.0f / 256.0f);
    float var = sq * (1.0f / 256.0f) - mean * mean;
    float rstd = rsqrtf(var + 1e-5f);
    float4 g = *(const float4*)&qg[d0];
    float4 bb = *(const float4*)&qb[d0];
    short4 o;
    o.x = f2bf((acc.x - mean) * rstd * g.x + bb.x);
    o.y = f2bf((acc.y - mean) * rstd * g.y + bb.y);
    o.z = f2bf((acc.z - mean) * rstd * g.z + bb.z);
    o.w = f2bf((acc.w - mean) * rstd * g.w + bb.w);
    *(short4*)&Qbf[(right ? 2097152L : 0L) + (long)bl * 256 + d0] = o;
}

// ---------------------------------------------------------------------------
// One 32-n chunk for 64 l rows (4 Q-frags), ONE side (L/R split across
// waves). Mask from LDS (fp32, bit-exact), XOR-swizzled n4^(l&7). Math
// identical to the round-5-proven kernel, minus the R half.
__device__ __forceinline__ void proc_chunk(
    short8 ak0, short8 ak1, short4v v00, short4v v01, short4v v10, short4v v11,
    const float* mlds, int sub, int quad, float inv2,
    const short8 (&bq)[4],
    f32x4 (&o)[4][2], float (&ps)[4]) {
    short8 av0, av1;
#pragma unroll
    for (int j = 0; j < 4; ++j) {
        av0[j] = v00[j]; av0[4 + j] = v01[j];
        av1[j] = v10[j]; av1[4 + j] = v11[j];
    }
    const int sw = (quad ^ (sub & 7)) << 2;
#pragma unroll
    for (int lt = 0; lt < 4; ++lt) {
        const int mi = ((lt * 16 + sub) << 5) + sw;
        float4 mk0 = *(const float4*)&mlds[mi];
        float4 mk1 = *(const float4*)&mlds[mi ^ 16];
        float m0x = mk0.x * inv2, m0y = mk0.y * inv2, m0z = mk0.z * inv2, m0w = mk0.w * inv2;
        float m1x = mk1.x * inv2, m1y = mk1.y * inv2, m1z = mk1.z * inv2, m1w = mk1.w * inv2;
        f32x4 c0 = {0.f, 0.f, 0.f, 0.f}, c1 = c0;
        c0 = __builtin_amdgcn_mfma_f32_16x16x32_bf16(ak0, bq[lt], c0, 0, 0, 0);
        c1 = __builtin_amdgcn_mfma_f32_16x16x32_bf16(ak1, bq[lt], c1, 0, 0, 0);
        float p0 = __builtin_amdgcn_exp2f(c0[0] * m0x);
        float p1 = __builtin_amdgcn_exp2f(c0[1] * m0y);
        float p2 = __builtin_amdgcn_exp2f(c0[2] * m0z);
        float p3 = __builtin_amdgcn_exp2f(c0[3] * m0w);
        float p4 = __builtin_amdgcn_exp2f(c1[0] * m1x);
        float p5 = __builtin_amdgcn_exp2f(c1[1] * m1y);
        float p6 = __builtin_amdgcn_exp2f(c1[2] * m1z);
        float p7 = __builtin_amdgcn_exp2f(c1[3] * m1w);
        ps[lt] += ((p0 + p1) + (p2 + p3)) + ((p4 + p5) + (p6 + p7));
        short8 p8;
        p8[0] = f2bf(p0); p8[1] = f2bf(p1); p8[2] = f2bf(p2); p8[3] = f2bf(p3);
        p8[4] = f2bf(p4); p8[5] = f2bf(p5); p8[6] = f2bf(p6); p8[7] = f2bf(p7);
        o[lt][0] = __builtin_amdgcn_mfma_f32_16x16x32_bf16(av0, p8, o[lt][0], 0, 0, 0);
        o[lt][1] = __builtin_amdgcn_mfma_f32_16x16x32_bf16(av1, p8, o[lt][1], 0, 0, 0);
    }
}

// ---------------------------------------------------------------------------
// MFMA cross-attention v4b: side-split, launch_bounds(512,1).
// Measured rounds 10-12: VGPR 112, no spill, FETCH 37.9MB, dur 72-79us
// (run-to-run variance +-4us) — barrier-pipeline-bound, kept as-is.
__global__ __launch_bounds__(512, 1) void attn_wave(const short* __restrict__ Qbf,
                                                    const short* __restrict__ Kbf,
                                                    const short* __restrict__ Vt,
                                                    const float* __restrict__ vis_mask,
                                                    const float* __restrict__ tau_p,
                                                    short* __restrict__ Fbf) {
    const int t = threadIdx.x;
    const int wid = t >> 6, lane = t & 63, sub = lane & 15, quad = lane >> 4;
    // bijective XCD swizzle over 512 blocks (64 per XCD)
    const int gb = ((blockIdx.x & 7) << 6) | (blockIdx.x >> 3);
    const int b = gb >> 4;            // 0..31
    const int lb = (gb >> 2) & 3;     // 0..3  (64-l block)
    const int hp = gb & 3;            // 0..3  (h pair)
    const int wh = wid >> 2;          // h in pair
    const int side = (wid >> 1) & 1;  // 0 = L, 1 = R
    const int nh = wid & 1;           // n-half
    const int h = hp * 2 + wh;        // 0..7
    const int l0 = lb * 64;
    float tau = fminf(fmaxf(tau_p[0], 0.25f), 4.0f);
    const float inv2 = 1.4426950408889634f / (5.656854249492381f * tau);

    // mask LDS: [2 buf][2 nh][64 l][8 n4'][4] floats = 32 KB, n4' = n4^(l&7)
    __shared__ float mbuf[2 * 4096];
    // combine buffer: pair p = (wh,side), payload o(32)+ps(4) @ stride 40
    __shared__ float red[4][64][40];

    // staging precompute: thread t owns 16B slots s0=2t, s1=2t+1
    const int s0 = t * 2;
    const int l_s = (s0 >> 3) & 63, nh_s = s0 >> 9;
    const int n4a = s0 & 7, n4b = n4a + 1;
    const float* mrow0 = vis_mask + (long)(b * 256 + l0 + l_s) * 1024 + nh_s * 512 + 4 * (n4a ^ (l_s & 7));
    const float* mrow1 = vis_mask + (long)(b * 256 + l0 + l_s) * 1024 + nh_s * 512 + 4 * (n4b ^ (l_s & 7));
    float* mdst0 = mbuf + nh_s * 2048 + l_s * 32 + n4a * 4;
    float* mdst1 = mbuf + nh_s * 2048 + l_s * 32 + n4b * 4;

    // Q B-frags for 4 l-tiles, this wave's side only
    const short* Qside = Qbf + (side ? 2097152L : 0L);
    short8 bq[4];
#pragma unroll
    for (int lt = 0; lt < 4; ++lt) {
        const long qoff = (long)(b * 256 + l0 + lt * 16 + sub) * 256 + h * 32 + quad * 8;
        bq[lt] = *(const short8*)&Qside[qoff];
    }

    const short* Kb = Kbf + (long)b * 262144 + h * 32;            // + n*256 + quad*8
    const short* Vb = Vt + (long)(b * 8 + h) * 32768;             // Vt[dh][n]
    const float* mld = mbuf + nh * 2048;                          // this wave's nh half

    f32x4 o[4][2];
    float ps[4];
#pragma unroll
    for (int lt = 0; lt < 4; ++lt) {
        o[lt][0] = (f32x4){0.f, 0.f, 0.f, 0.f}; o[lt][1] = o[lt][0];
        ps[lt] = 0.f;
    }

    const int nbeg = nh << 9;   // n-half [nbeg, nbeg+512)

#define LOADK(A0, A1, N)                                                      \
    A0 = *(const short8*)&Kb[(long)((N) + sub) * 256 + quad * 8];             \
    A1 = *(const short8*)&Kb[(long)((N) + 16 + sub) * 256 + quad * 8];
#define LOADV(W00, W01, W10, W11, N)                                          \
    W00 = *(const short4v*)&Vb[(long)sub * 1024 + (N) + quad * 4];            \
    W01 = *(const short4v*)&Vb[(long)sub * 1024 + (N) + 16 + quad * 4];       \
    W10 = *(const short4v*)&Vb[(long)(16 + sub) * 1024 + (N) + quad * 4];     \
    W11 = *(const short4v*)&Vb[(long)(16 + sub) * 1024 + (N) + 16 + quad * 4];

    short8 ak0A, ak1A, ak0B, ak1B;
    short4v v00A, v01A, v10A, v11A, v00B, v01B, v10B, v11B;
    float4 mr0, mr1;

    // prologue: stage mask chunk 0 into buf0, prefetch K/V chunk 0
    mr0 = *(const float4*)&mrow0[0];
    mr1 = *(const float4*)&mrow1[0];
    *(float4*)&mdst0[0] = mr0;
    *(float4*)&mdst1[0] = mr1;
    LOADK(ak0A, ak1A, nbeg)
    LOADV(v00A, v01A, v10A, v11A, nbeg)
    __syncthreads();

#pragma unroll 1
    for (int j = 0; j < 8; ++j) {
        const int n0 = nbeg + j * 64;
        // ---- chunk 2j (mask buf0) ----
        LOADK(ak0B, ak1B, n0 + 32)
        LOADV(v00B, v01B, v10B, v11B, n0 + 32)
        {   // load mask chunk 2j+1 (always valid) into regs
            const int nrel = j * 64 + 32;
            mr0 = *(const float4*)&mrow0[nrel];
            mr1 = *(const float4*)&mrow1[nrel];
        }
        proc_chunk(ak0A, ak1A, v00A, v01A, v10A, v11A, mld, sub, quad, inv2,
                   bq, o, ps);
        *(float4*)&mdst0[4096] = mr0;       // write chunk 2j+1 -> buf1
        *(float4*)&mdst1[4096] = mr1;
        __syncthreads();
        // ---- chunk 2j+1 (mask buf1) ----
        const int nx = (j < 7) ? n0 + 64 : nbeg;     // last prefetch = dummy (hot)
        LOADK(ak0A, ak1A, nx)
        LOADV(v00A, v01A, v10A, v11A, nx)
        {   // load mask chunk 2j+2 (dummy reload of chunk0 at j=7)
            const int nrel = (j < 7) ? j * 64 + 64 : 0;
            mr0 = *(const float4*)&mrow0[nrel];
            mr1 = *(const float4*)&mrow1[nrel];
        }
        proc_chunk(ak0B, ak1B, v00B, v01B, v10B, v11B, mld + 4096, sub, quad, inv2,
                   bq, o, ps);
        *(float4*)&mdst0[0] = mr0;          // write chunk 2j+2 -> buf0 (dummy at j=7)
        *(float4*)&mdst1[0] = mr1;
        __syncthreads();
    }
#undef LOADK
#undef LOADV

    // full row-sums per l-tile for l = sub (combine the 4 quads)
#pragma unroll
    for (int lt = 0; lt < 4; ++lt) {
        ps[lt] += __shfl_xor(ps[lt], 16, 64);
        ps[lt] += __shfl_xor(ps[lt], 32, 64);
    }

    // cross n-half combine within (wh, side) pair: nh==1 publishes,
    // one barrier, nh==0 adds. layout per lane: [0..31]=o, [32..35]=ps.
    const int pr = wid >> 1;   // pair index = wh*2+side
    if (nh == 1) {
        float* p = &red[pr][lane][0];
#pragma unroll
        for (int lt = 0; lt < 4; ++lt) {
            *(f32x4*)(p + lt * 8) = o[lt][0];
            *(f32x4*)(p + lt * 8 + 4) = o[lt][1];
            p[32 + lt] = ps[lt];
        }
    }
    __syncthreads();
    if (nh == 1) return;
    {
        const float* p = &red[pr][lane][0];
#pragma unroll
        for (int lt = 0; lt < 4; ++lt) {
            f32x4 e0 = *(const f32x4*)(p + lt * 8);
            f32x4 e1 = *(const f32x4*)(p + lt * 8 + 4);
#pragma unroll
            for (int q = 0; q < 4; ++q) {
                o[lt][0][q] += e0[q];
                o[lt][1][q] += e1[q];
            }
            ps[lt] += p[32 + lt];
        }
    }

    // O^T[4*quad+r (+16)][l] -> F[b,l][h*32 + 4*quad + r (+16)]
    short* Fside = Fbf + (side ? 2097152L : 0L);
#pragma unroll
    for (int lt = 0; lt < 4; ++lt) {
        const long fo = (long)(b * 256 + l0 + lt * 16 + sub) * 256 + h * 32 + quad * 4;
        const float rS = 1.0f / ps[lt];
        short4v s0v, s1v;
#pragma unroll
        for (int r = 0; r < 4; ++r) { s0v[r] = f2bf(o[lt][0][r] * rS); s1v[r] = f2bf(o[lt][1][r] * rS); }
        *(short4v*)&Fside[fo] = s0v;
        *(short4v*)&Fside[fo + 16] = s1v;
    }
}

// ---------------------------------------------------------------------------
// Loss: wave per (b,l) pair; block-level reduce, one plain store per block.
__global__ __launch_bounds__(256) void loss_pair(const float* __restrict__ logits,
                                                 const float* __restrict__ tgt_mask,
                                                 float* __restrict__ partials) {
    const int wid = threadIdx.x >> 6, lane = threadIdx.x & 63;
    const int pid = blockIdx.x * 4 + wid;   // 0..8159
    const int b = pid / 255, l = pid - b * 255;
    const float* ll = logits + (long)(b * 256 + l) * 512;
    const float* lr = logits + 4194304 + (long)(b * 256 + l + 1) * 512;
    float a[8], c[8];
#pragma unroll
    for (int j = 0; j < 8; ++j) {
        a[j] = ll[lane + 64 * j] * 0.5f;
        c[j] = lr[lane + 64 * j] * 0.5f;
    }
    float ml = -1e30f, mr = -1e30f;
#pragma unroll
    for (int j = 0; j < 8; ++j) { ml = fmaxf(ml, a[j]); mr = fmaxf(mr, c[j]); }
#pragma unroll
    for (int off = 32; off; off >>= 1) {
        ml = fmaxf(ml, __shfl_xor(ml, off, 64));
        mr = fmaxf(mr, __shfl_xor(mr, off, 64));
    }
    float sl = 0.f, sr = 0.f;
#pragma unroll
    for (int j = 0; j < 8; ++j) {
        a[j] = __expf(a[j] - ml); sl += a[j];
        c[j] = __expf(c[j] - mr); sr += c[j];
    }
#pragma unroll
    for (int off = 32; off; off >>= 1) {
        sl += __shfl_xor(sl, off, 64);
        sr += __shfl_xor(sr, off, 64);
    }
    float rl = 1.0f / sl, rr = 1.0f / sr;
    float sq = 0.f;
#pragma unroll
    for (int j = 0; j < 8; ++j) {
        float d = a[j] * rl - c[j] * rr;
        sq += d * d;
    }
#pragma unroll
    for (int off = 32; off; off >>= 1) sq += __shfl_xor(sq, off, 64);

    __shared__ float sred[4];
    if (lane == 0) sred[wid] = sq * tgt_mask[b * 256 + l];
    __syncthreads();
    if (threadIdx.x == 0)
        partials[blockIdx.x] = (sred[0] + sred[1]) + (sred[2] + sred[3]);
}

__global__ __launch_bounds__(256) void loss_final(const float* __restrict__ tgt_mask,
                                                  const float* __restrict__ partials,
                                                  float* __restrict__ outp) {
    const int t = threadIdx.x;
    float s = 0.f, acc = 0.f;
    for (int i = t; i < 32 * 255; i += 256) {
        int b = i / 255, l = i % 255;
        s += tgt_mask[b * 256 + l];
    }
    for (int i = t; i < 2040; i += 256) acc += partials[i];
    __shared__ float red[256];
    __shared__ float reda[256];
    red[t] = s;
    reda[t] = acc;
    __syncthreads();
    for (int st = 128; st; st >>= 1) {
        if (t < st) { red[t] += red[t + st]; reda[t] += reda[t + st]; }
        __syncthreads();
    }
    if (t == 0) outp[0] = 0.1f * reda[0] / fmaxf(red[0], 1.0f);
}

// ---------------------------------------------------------------------------
extern "C" void kernel_launch(void* const* d_in, const int* in_sizes, int n_in,
                              void* d_out, int out_size, void* d_ws, size_t ws_size,
                              hipStream_t stream) {
    const float* vis_tokens = (const float*)d_in[0];
    const int* idsL = (const int*)d_in[1];
    const int* idsR = (const int*)d_in[2];
    const float* tgt_mask = (const float*)d_in[4];
    const float* vis_mask = (const float*)d_in[5];
    const float* emb_w = (const float*)d_in[6];
    const float* dirL = (const float*)d_in[7];
    const float* dirR = (const float*)d_in[8];
    const float* tp_w = (const float*)d_in[9];
    const float* tp_b = (const float*)d_in[10];
    const float* q_g = (const float*)d_in[11];
    const float* q_b = (const float*)d_in[12];
    const float* k_w = (const float*)d_in[13];
    const float* k_b = (const float*)d_in[14];
    const float* v_w = (const float*)d_in[15];
    const float* v_b = (const float*)d_in[16];
    const float* kv_g = (const float*)d_in[17];
    const float* kv_b = (const float*)d_in[18];
    const float* tau = (const float*)d_in[19];
    const float* cls_b = (const float*)d_in[20];
    const float* conv_l = (const float*)d_in[21];
    const float* conv_r = (const float*)d_in[22];
    float* out = (float*)d_out;

    // ---- workspace layout (visbf slot retired; layout kept stable) ----
    short* sws = (short*)d_ws;
    short* embbf = sws + 8388608;               // 131,072
    short* kwbf  = embbf + 131072;              // 65,536
    short* vwbf  = kwbf + 65536;                // 65,536
    short* Kbf   = vwbf + 65536;                // 8,388,608
    short* Vt    = Kbf + 8388608;               // 8,388,608
    short* Qbf   = Vt + 8388608;                // 4,194,304 (L|R)
    short* Fbf   = Qbf + 4194304;               // 4,194,304 (L|R)
    float* wfT   = (float*)(Fbf + 4194304);     // 10 slices x 65536
    float* Ms    = wfT + 655360;                // 10 x 65536
    float* Pp    = Ms + 655360;                 // 10 x 131072
    float* bias_l = Pp + 1310720;
    float* bias_r = bias_l + 256;
    float* partials = bias_r + 256;             // 2040 floats

    // ---- merged prep: cvt3 + build_wfold + bias_dir in one launch ----
    prep<<<784, 256, 0, stream>>>(emb_w, k_w, v_w, embbf, kwbf, vwbf,
                                  conv_l, conv_r, wfT,
                                  tp_w, tp_b, dirL, dirR, bias_l, bias_r);

    // ---- ctx path: Ms -> P (fp32, small) ----
    gemm64<false><<<dim3(4, 4, 10), 256, 0, stream>>>(tp_w, wfT, nullptr, Ms, 256, 256, 0, 65536, 65536);
    gemm64<false><<<dim3(8, 4, 10), 256, 0, stream>>>(emb_w, Ms, nullptr, Pp, 256, 256, 0, 65536, 131072);
    q_build<<<dim3(2048, 2), 256, 0, stream>>>(idsL, idsR, Pp, bias_l, bias_r, q_g, q_b, Qbf);

    // ---- K/V projections + LN fused (fp32 A read + inline cvt) ----
    gemm_ln<<<dim3(512, 2), 256, 0, stream>>>(vis_tokens, kwbf, vwbf, k_b, v_b, kv_g, kv_b, Kbf, Vt);

    // ---- MFMA cross-attention v4b: side-split, (512,1) ----
    attn_wave<<<512, 512, 0, stream>>>(Qbf, Kbf, Vt, vis_mask, tau, Fbf);

    // ---- tied classifier logits into d_out+1 (proven 64x64-block version) ----
    gemm_bf<<<dim3(128, 8, 2), 256, 0, stream>>>(Fbf, embbf, cls_b, out + 1, 256, 512,
                                                 2097152, 4194304);

    // ---- SGM agreement loss (atomic-free two-stage reduction) ----
    loss_pair<<<2040, 256, 0, stream>>>(out + 1, tgt_mask, partials);
    loss_final<<<1, 256, 0, stream>>>(tgt_mask, partials, out);
}